// Round 1
// baseline (863.651 us; speedup 1.0000x reference)
//
#include <hip/hip_runtime.h>

#define BD 16
#define EMBD 128
#define H0D 256
#define UPD 512
#define RAD 60
#define PATCHD 120
#define COEFF 1.5f

// ---------------- small helpers ----------------

__device__ __forceinline__ float bsample(const float* __restrict__ img, int H, int W,
                                         float gx, float gy) {
    // grid_sample_bilinear semantics (align_corners=False style, zero pad)
    float xs = ((gx + 1.f) * (float)W - 1.f) * 0.5f;
    float ys = ((gy + 1.f) * (float)H - 1.f) * 0.5f;
    float x0f = floorf(xs), y0f = floorf(ys);
    float wx = xs - x0f, wy = ys - y0f;
    int x0 = (int)x0f, y0 = (int)y0f;
    bool vx0 = (x0 >= 0) && (x0 <= W - 1);
    bool vx1 = (x0 + 1 >= 0) && (x0 + 1 <= W - 1);
    bool vy0 = (y0 >= 0) && (y0 <= H - 1);
    bool vy1 = (y0 + 1 >= 0) && (y0 + 1 <= H - 1);
    int xi0 = min(max(x0, 0), W - 1);
    int xi1 = min(max(x0 + 1, 0), W - 1);
    int yi0 = min(max(y0, 0), H - 1);
    int yi1 = min(max(y0 + 1, 0), H - 1);
    float v00 = (vy0 && vx0) ? img[yi0 * W + xi0] : 0.f;
    float v01 = (vy0 && vx1) ? img[yi0 * W + xi1] : 0.f;
    float v10 = (vy1 && vx0) ? img[yi1 * W + xi0] : 0.f;
    float v11 = (vy1 && vx1) ? img[yi1 * W + xi1] : 0.f;
    return v00 * (1.f - wy) * (1.f - wx) + v01 * (1.f - wy) * wx +
           v10 * wy * (1.f - wx) + v11 * wy * wx;
}

// ---------------- kernels ----------------

// invert [[a,b,0],[c,d,0],[0,0,1]] -> take top 2 rows (2x3).
__global__ void k_inv(const float* __restrict__ ss, const float* __restrict__ rot,
                      float* __restrict__ invbuf) {
    int b = threadIdx.x;
    if (b < BD) {
        {
            const float* A = ss + b * 6;
            float a = A[0], bb = A[1], c = A[3], d = A[4];
            float det = a * d - bb * c;
            float* o = invbuf + b * 6;
            o[0] = d / det; o[1] = -bb / det; o[2] = 0.f;
            o[3] = -c / det; o[4] = a / det; o[5] = 0.f;
        }
        {
            const float* A = rot + b * 6;
            float a = A[0], bb = A[1], c = A[3], d = A[4];
            float det = a * d - bb * c;
            float* o = invbuf + 96 + b * 6;
            o[0] = d / det; o[1] = -bb / det; o[2] = 0.f;
            o[3] = -c / det; o[4] = a / det; o[5] = 0.f;
        }
    }
}

// base[b, n] = relu(sum_e k_out[b,e] * W_dec[e,n]);  n in [0,65536)
__global__ __launch_bounds__(256) void k_gemm(const float* __restrict__ kout,
                                              const float* __restrict__ Wd,
                                              float* __restrict__ base) {
    __shared__ float sk[BD * EMBD];
    int t = threadIdx.x;
    for (int i = t; i < BD * EMBD; i += 256) sk[i] = kout[i];
    __syncthreads();
    int n = blockIdx.x * 256 + t;
    float acc[BD];
#pragma unroll
    for (int b = 0; b < BD; b++) acc[b] = 0.f;
    for (int e = 0; e < EMBD; e++) {
        float w = Wd[(size_t)e * (H0D * H0D) + n];
#pragma unroll
        for (int b = 0; b < BD; b++) acc[b] += sk[b * EMBD + e] * w;
    }
#pragma unroll
    for (int b = 0; b < BD; b++)
        base[(size_t)b * (H0D * H0D) + n] = fmaxf(acc[b], 0.f);
}

// bilinear resize 256x256 -> 512x512 per batch
__global__ void k_resize(const float* __restrict__ base, float* __restrict__ out) {
    int idx = blockIdx.x * blockDim.x + threadIdx.x;
    if (idx >= BD * UPD * UPD) return;
    int b = idx >> 18;
    int p = idx & (UPD * UPD - 1);
    int yo = p >> 9, xo = p & 511;
    float ysf = fminf(fmaxf(((float)yo + 0.5f) * 0.5f - 0.5f, 0.f), 255.f);
    float xsf = fminf(fmaxf(((float)xo + 0.5f) * 0.5f - 0.5f, 0.f), 255.f);
    int y0 = (int)floorf(ysf), x0 = (int)floorf(xsf);
    int y1 = min(y0 + 1, H0D - 1), x1 = min(x0 + 1, H0D - 1);
    float wy = ysf - (float)y0, wx = xsf - (float)x0;
    const float* img = base + (size_t)b * (H0D * H0D);
    float Ia = img[y0 * H0D + x0], Ib = img[y0 * H0D + x1];
    float Ic = img[y1 * H0D + x0], Id = img[y1 * H0D + x1];
    out[idx] = Ia * (1.f - wy) * (1.f - wx) + Ib * (1.f - wy) * wx +
               Ic * wy * (1.f - wx) + Id * wy * wx;
}

// generic affine grid-sample over 512x512; inBstride=0 broadcasts input over batch
__global__ void k_sample(const float* __restrict__ in, size_t inBstride,
                         const float* __restrict__ theta, float* __restrict__ out,
                         float* __restrict__ out2) {
    int idx = blockIdx.x * blockDim.x + threadIdx.x;
    if (idx >= BD * UPD * UPD) return;
    int b = idx >> 18;
    int p = idx & (UPD * UPD - 1);
    int yo = p >> 9, xo = p & 511;
    const float* th = theta + b * 6;
    float X = ((float)xo + 0.5f) * (2.f / UPD) - 1.f;
    float Y = ((float)yo + 0.5f) * (2.f / UPD) - 1.f;
    float gx = th[0] * X + th[1] * Y + th[2];
    float gy = th[3] * X + th[4] * Y + th[5];
    float v = bsample(in + (size_t)b * inBstride, UPD, UPD, gx, gy);
    out[idx] = v;
    if (out2) out2[idx] = v;
}

// sample + threshold >= 0.5 into uint8
__global__ void k_sample_thresh(const float* __restrict__ in,
                                const float* __restrict__ theta,
                                unsigned char* __restrict__ out) {
    int idx = blockIdx.x * blockDim.x + threadIdx.x;
    if (idx >= BD * UPD * UPD) return;
    int b = idx >> 18;
    int p = idx & (UPD * UPD - 1);
    int yo = p >> 9, xo = p & 511;
    const float* th = theta + b * 6;
    float X = ((float)xo + 0.5f) * (2.f / UPD) - 1.f;
    float Y = ((float)yo + 0.5f) * (2.f / UPD) - 1.f;
    float gx = th[0] * X + th[1] * Y + th[2];
    float gy = th[3] * X + th[4] * Y + th[5];
    float v = bsample(in + (size_t)b * (UPD * UPD), UPD, UPD, gx, gy);
    out[idx] = (v >= 0.5f) ? 1 : 0;
}

// per-batch reduction: S_new = sum(pred_in * m), S_m = sum(m)
__global__ __launch_bounds__(1024) void k_stats1(const float* __restrict__ pred_in,
                                                 const unsigned char* __restrict__ rm,
                                                 float* __restrict__ stats) {
    int b = blockIdx.x;
    const float* pi = pred_in + (size_t)b * (UPD * UPD);
    const unsigned char* m = rm + (size_t)b * (UPD * UPD);
    float s_new = 0.f, s_m = 0.f;
    for (int p = threadIdx.x; p < UPD * UPD; p += 1024) {
        float mm = (float)m[p];
        s_new += pi[p] * mm;
        s_m += mm;
    }
    __shared__ float r1[1024], r2[1024];
    r1[threadIdx.x] = s_new;
    r2[threadIdx.x] = s_m;
    __syncthreads();
    for (int s = 512; s > 0; s >>= 1) {
        if (threadIdx.x < (unsigned)s) {
            r1[threadIdx.x] += r1[threadIdx.x + s];
            r2[threadIdx.x] += r2[threadIdx.x + s];
        }
        __syncthreads();
    }
    if (threadIdx.x == 0) {
        stats[b * 8 + 0] = r1[0];
        stats[b * 8 + 1] = r2[0];
    }
}

// per-batch: centroid of w = new_img where (m>0 && new_img > COEF*mean)
__global__ __launch_bounds__(1024) void k_stats2(const float* __restrict__ pred_in,
                                                 const unsigned char* __restrict__ rm,
                                                 float* __restrict__ stats) {
    int b = blockIdx.x;
    const float* pi = pred_in + (size_t)b * (UPD * UPD);
    const unsigned char* m = rm + (size_t)b * (UPD * UPD);
    float mean = stats[b * 8 + 0] / fmaxf(stats[b * 8 + 1], 1.f);
    float thr = COEFF * mean;
    float tot = 0.f, sx = 0.f, sy = 0.f;
    for (int p = threadIdx.x; p < UPD * UPD; p += 1024) {
        float mm = (float)m[p];
        float ni = pi[p] * mm;
        bool sel = (mm > 0.f) && (ni > thr);
        float w = sel ? ni : 0.f;
        int i = p >> 9, j = p & 511;
        tot += w;
        sx += w * (float)i;
        sy += w * (float)j;
    }
    __shared__ float r1[1024], r2[1024], r3[1024];
    r1[threadIdx.x] = tot;
    r2[threadIdx.x] = sx;
    r3[threadIdx.x] = sy;
    __syncthreads();
    for (int s = 512; s > 0; s >>= 1) {
        if (threadIdx.x < (unsigned)s) {
            r1[threadIdx.x] += r1[threadIdx.x + s];
            r2[threadIdx.x] += r2[threadIdx.x + s];
            r3[threadIdx.x] += r3[threadIdx.x + s];
        }
        __syncthreads();
    }
    if (threadIdx.x == 0) {
        float t = r1[0] + 1e-8f;
        float cx = r2[0] / t;
        float cy = r3[0] / t;
        float cxi = fminf(fmaxf(rintf(cx), (float)RAD), (float)(UPD - RAD));
        float cyi = fminf(fmaxf(rintf(cy), (float)RAD), (float)(UPD - RAD));
        stats[b * 8 + 2] = cxi;
        stats[b * 8 + 3] = cyi;
    }
}

// extract 120x120 patch from img at (cxi-60, cyi-60), divide dot circle by adj
__global__ void k_extract(const float* __restrict__ img, const float* __restrict__ stats,
                          const float* __restrict__ adj, float* __restrict__ patch) {
    int b = blockIdx.x;
    int cxi = (int)stats[b * 8 + 2], cyi = (int)stats[b * 8 + 3];
    float a = adj[b];
    const float* im = img + (size_t)b * (UPD * UPD);
    float* pp = patch + b * PATCHD * PATCHD;
    for (int p = threadIdx.x; p < PATCHD * PATCHD; p += blockDim.x) {
        int i = p / PATCHD, j = p - i * PATCHD;
        float v = im[(cxi - RAD + i) * UPD + (cyi - RAD + j)];
        int di = i - RAD, dj = j - RAD;
        if (di * di + dj * dj <= 100) v /= a;  // _DOT = 10
        pp[p] = v;
    }
}

// resample the patch with affine inv1 and write back into img region
__global__ void k_apply(const float* __restrict__ patch, const float* __restrict__ stats,
                        const float* __restrict__ theta, float* __restrict__ img) {
    int b = blockIdx.x;
    int cxi = (int)stats[b * 8 + 2], cyi = (int)stats[b * 8 + 3];
    const float* th = theta + b * 6;
    const float* pp = patch + b * PATCHD * PATCHD;
    float* im = img + (size_t)b * (UPD * UPD);
    for (int p = threadIdx.x; p < PATCHD * PATCHD; p += blockDim.x) {
        int i = p / PATCHD, j = p - i * PATCHD;
        float X = ((float)j + 0.5f) * (2.f / PATCHD) - 1.f;
        float Y = ((float)i + 0.5f) * (2.f / PATCHD) - 1.f;
        float gx = th[0] * X + th[1] * Y + th[2];
        float gy = th[3] * X + th[4] * Y + th[5];
        float v = bsample(pp, PATCHD, PATCHD, gx, gy);
        im[(cxi - RAD + i) * UPD + (cyi - RAD + j)] = v;
    }
}

// ---------------- launch ----------------

extern "C" void kernel_launch(void* const* d_in, const int* in_sizes, int n_in,
                              void* d_out, int out_size, void* d_ws, size_t ws_size,
                              hipStream_t stream) {
    const float* x = (const float*)d_in[0];
    const float* k_out = (const float*)d_in[1];
    const float* W_dec = (const float*)d_in[2];
    const float* ss = (const float*)d_in[3];
    const float* rot = (const float*)d_in[4];
    const float* masks = (const float*)d_in[5];
    const float* adj = (const float*)d_in[6];

    float* out = (float*)d_out;
    const size_t NX = (size_t)BD * H0D * H0D;      // 1,048,576
    const size_t P = (size_t)BD * UPD * UPD;       // 4,194,304
    float* out_x = out;
    float* out_base = out + NX;
    float* out_img = out + NX + P;

    float* ws = (float*)d_ws;
    float* slotA = ws;                 // pred_rot, later rm1        (P floats)
    float* slotB = ws + P;             // pred_in (persistent)       (P floats)
    float* slotC = ws + 2 * P;         // base (P/4 floats), later rm (P bytes)
    unsigned char* rm = (unsigned char*)slotC;
    float* invbuf = ws + 2 * P + P / 4;  // 192 floats
    float* stats = invbuf + 192;         // 128 floats
    float* patch = stats + 128;          // 16*120*120 = 230,400 floats

    // output 0: passthrough x
    hipMemcpyAsync(out_x, x, NX * sizeof(float), hipMemcpyDeviceToDevice, stream);

    k_inv<<<1, 64, 0, stream>>>(ss, rot, invbuf);
    float* inv1 = invbuf;
    float* inv2 = invbuf + 96;

    k_gemm<<<(H0D * H0D) / 256, 256, 0, stream>>>(k_out, W_dec, slotC);
    k_resize<<<(int)(P / 256), 256, 0, stream>>>(slotC, out_base);

    // pred_rot = sample(base_inp, inv2)
    k_sample<<<(int)(P / 256), 256, 0, stream>>>(out_base, (size_t)(UPD * UPD), inv2,
                                                 slotA, nullptr);
    // pred_in = sample(pred_rot, inv1); dual-write initial img
    k_sample<<<(int)(P / 256), 256, 0, stream>>>(slotA, (size_t)(UPD * UPD), inv1,
                                                 slotB, out_img);

    for (int j = 0; j < 4; j++) {
        // rm1 = sample(mask_j broadcast, inv2)
        k_sample<<<(int)(P / 256), 256, 0, stream>>>(masks + (size_t)j * (UPD * UPD),
                                                     (size_t)0, inv2, slotA, nullptr);
        // rm = sample(rm1, inv1) >= 0.5
        k_sample_thresh<<<(int)(P / 256), 256, 0, stream>>>(slotA, inv1, rm);
        k_stats1<<<BD, 1024, 0, stream>>>(slotB, rm, stats);
        k_stats2<<<BD, 1024, 0, stream>>>(slotB, rm, stats);
        k_extract<<<BD, 256, 0, stream>>>(out_img, stats, adj, patch);
        k_apply<<<BD, 256, 0, stream>>>(patch, stats, inv1, out_img);
    }
}

// Round 2
// 396.376 us; speedup vs baseline: 2.1789x; 2.1789x over previous
//
#include <hip/hip_runtime.h>

#define BD 16
#define EMBD 128
#define H0D 256
#define UPD 512
#define RAD 60
#define PATCHD 120
#define COEFF 1.5f
#define NB 256          // partial-reduction blocks per batch
#define CHUNK 1024      // pixels per partial block (262144 / 256)

// ---------------- small helpers ----------------

__device__ __forceinline__ float bsample(const float* __restrict__ img, int H, int W,
                                         float gx, float gy) {
    float xs = ((gx + 1.f) * (float)W - 1.f) * 0.5f;
    float ys = ((gy + 1.f) * (float)H - 1.f) * 0.5f;
    float x0f = floorf(xs), y0f = floorf(ys);
    float wx = xs - x0f, wy = ys - y0f;
    int x0 = (int)x0f, y0 = (int)y0f;
    bool vx0 = (x0 >= 0) && (x0 <= W - 1);
    bool vx1 = (x0 + 1 >= 0) && (x0 + 1 <= W - 1);
    bool vy0 = (y0 >= 0) && (y0 <= H - 1);
    bool vy1 = (y0 + 1 >= 0) && (y0 + 1 <= H - 1);
    int xi0 = min(max(x0, 0), W - 1);
    int xi1 = min(max(x0 + 1, 0), W - 1);
    int yi0 = min(max(y0, 0), H - 1);
    int yi1 = min(max(y0 + 1, 0), H - 1);
    float v00 = (vy0 && vx0) ? img[yi0 * W + xi0] : 0.f;
    float v01 = (vy0 && vx1) ? img[yi0 * W + xi1] : 0.f;
    float v10 = (vy1 && vx0) ? img[yi1 * W + xi0] : 0.f;
    float v11 = (vy1 && vx1) ? img[yi1 * W + xi1] : 0.f;
    return v00 * (1.f - wy) * (1.f - wx) + v01 * (1.f - wy) * wx +
           v10 * wy * (1.f - wx) + v11 * wy * wx;
}

// ---------------- kernels ----------------

__global__ void k_inv(const float* __restrict__ ss, const float* __restrict__ rot,
                      float* __restrict__ invbuf) {
    int b = threadIdx.x;
    if (b < BD) {
        {
            const float* A = ss + b * 6;
            float a = A[0], bb = A[1], c = A[3], d = A[4];
            float det = a * d - bb * c;
            float* o = invbuf + b * 6;
            o[0] = d / det; o[1] = -bb / det; o[2] = 0.f;
            o[3] = -c / det; o[4] = a / det; o[5] = 0.f;
        }
        {
            const float* A = rot + b * 6;
            float a = A[0], bb = A[1], c = A[3], d = A[4];
            float det = a * d - bb * c;
            float* o = invbuf + 96 + b * 6;
            o[0] = d / det; o[1] = -bb / det; o[2] = 0.f;
            o[3] = -c / det; o[4] = a / det; o[5] = 0.f;
        }
    }
}

__global__ __launch_bounds__(256) void k_gemm(const float* __restrict__ kout,
                                              const float* __restrict__ Wd,
                                              float* __restrict__ base) {
    __shared__ float sk[BD * EMBD];
    int t = threadIdx.x;
    for (int i = t; i < BD * EMBD; i += 256) sk[i] = kout[i];
    __syncthreads();
    int n = blockIdx.x * 256 + t;
    float acc[BD];
#pragma unroll
    for (int b = 0; b < BD; b++) acc[b] = 0.f;
    for (int e = 0; e < EMBD; e++) {
        float w = Wd[(size_t)e * (H0D * H0D) + n];
#pragma unroll
        for (int b = 0; b < BD; b++) acc[b] += sk[b * EMBD + e] * w;
    }
#pragma unroll
    for (int b = 0; b < BD; b++)
        base[(size_t)b * (H0D * H0D) + n] = fmaxf(acc[b], 0.f);
}

__global__ void k_resize(const float* __restrict__ base, float* __restrict__ out) {
    int idx = blockIdx.x * blockDim.x + threadIdx.x;
    if (idx >= BD * UPD * UPD) return;
    int b = idx >> 18;
    int p = idx & (UPD * UPD - 1);
    int yo = p >> 9, xo = p & 511;
    float ysf = fminf(fmaxf(((float)yo + 0.5f) * 0.5f - 0.5f, 0.f), 255.f);
    float xsf = fminf(fmaxf(((float)xo + 0.5f) * 0.5f - 0.5f, 0.f), 255.f);
    int y0 = (int)floorf(ysf), x0 = (int)floorf(xsf);
    int y1 = min(y0 + 1, H0D - 1), x1 = min(x0 + 1, H0D - 1);
    float wy = ysf - (float)y0, wx = xsf - (float)x0;
    const float* img = base + (size_t)b * (H0D * H0D);
    float Ia = img[y0 * H0D + x0], Ib = img[y0 * H0D + x1];
    float Ic = img[y1 * H0D + x0], Id = img[y1 * H0D + x1];
    out[idx] = Ia * (1.f - wy) * (1.f - wx) + Ib * (1.f - wy) * wx +
               Ic * wy * (1.f - wx) + Id * wy * wx;
}

__global__ void k_sample(const float* __restrict__ in, size_t inBstride,
                         const float* __restrict__ theta, float* __restrict__ out,
                         float* __restrict__ out2) {
    int idx = blockIdx.x * blockDim.x + threadIdx.x;
    if (idx >= BD * UPD * UPD) return;
    int b = idx >> 18;
    int p = idx & (UPD * UPD - 1);
    int yo = p >> 9, xo = p & 511;
    const float* th = theta + b * 6;
    float X = ((float)xo + 0.5f) * (2.f / UPD) - 1.f;
    float Y = ((float)yo + 0.5f) * (2.f / UPD) - 1.f;
    float gx = th[0] * X + th[1] * Y + th[2];
    float gy = th[3] * X + th[4] * Y + th[5];
    float v = bsample(in + (size_t)b * inBstride, UPD, UPD, gx, gy);
    out[idx] = v;
    if (out2) out2[idx] = v;
}

// rm = (sample(rm1, inv1) >= 0.5); also per-block partials of
// s_new = sum(pred_in * rm), s_m = sum(rm)
__global__ __launch_bounds__(256) void k_sample_thresh_stats(
        const float* __restrict__ in, const float* __restrict__ theta,
        const float* __restrict__ pred_in, unsigned char* __restrict__ rm,
        float* __restrict__ part1) {
    int b = blockIdx.x >> 8;          // NB=256 blocks per batch
    int blk = blockIdx.x & (NB - 1);
    int t = threadIdx.x;
    int base = blk * CHUNK;
    const float* th = theta + b * 6;
    const float* img = in + (size_t)b * (UPD * UPD);
    const float* pi = pred_in + (size_t)b * (UPD * UPD);
    unsigned char* rmb = rm + (size_t)b * (UPD * UPD);
    float s_new = 0.f, s_m = 0.f;
#pragma unroll
    for (int k = 0; k < CHUNK / 256; k++) {
        int p = base + k * 256 + t;
        int yo = p >> 9, xo = p & 511;
        float X = ((float)xo + 0.5f) * (2.f / UPD) - 1.f;
        float Y = ((float)yo + 0.5f) * (2.f / UPD) - 1.f;
        float gx = th[0] * X + th[1] * Y + th[2];
        float gy = th[3] * X + th[4] * Y + th[5];
        float v = bsample(img, UPD, UPD, gx, gy);
        float mm = (v >= 0.5f) ? 1.f : 0.f;
        rmb[p] = (unsigned char)mm;
        s_new += pi[p] * mm;
        s_m += mm;
    }
    __shared__ float r1[256], r2[256];
    r1[t] = s_new; r2[t] = s_m;
    __syncthreads();
    for (int s = 128; s > 0; s >>= 1) {
        if (t < s) { r1[t] += r1[t + s]; r2[t] += r2[t + s]; }
        __syncthreads();
    }
    if (t == 0) {
        part1[(b * NB + blk) * 2 + 0] = r1[0];
        part1[(b * NB + blk) * 2 + 1] = r2[0];
    }
}

// reduce part1 -> thr (redundantly per block), then partial centroid sums
__global__ __launch_bounds__(256) void k_stats2p(
        const float* __restrict__ pred_in, const unsigned char* __restrict__ rm,
        const float* __restrict__ part1, float* __restrict__ part2) {
    int b = blockIdx.x >> 8;
    int blk = blockIdx.x & (NB - 1);
    int t = threadIdx.x;
    __shared__ float r1[256], r2[256], r3[256];
    r1[t] = part1[(b * NB + t) * 2 + 0];
    r2[t] = part1[(b * NB + t) * 2 + 1];
    __syncthreads();
    for (int s = 128; s > 0; s >>= 1) {
        if (t < s) { r1[t] += r1[t + s]; r2[t] += r2[t + s]; }
        __syncthreads();
    }
    float mean = r1[0] / fmaxf(r2[0], 1.f);
    float thr = COEFF * mean;
    __syncthreads();

    int base = blk * CHUNK;
    const float* pi = pred_in + (size_t)b * (UPD * UPD);
    const unsigned char* m = rm + (size_t)b * (UPD * UPD);
    float tot = 0.f, sx = 0.f, sy = 0.f;
#pragma unroll
    for (int k = 0; k < CHUNK / 256; k++) {
        int p = base + k * 256 + t;
        float mm = (float)m[p];
        float ni = pi[p] * mm;
        bool sel = (mm > 0.f) && (ni > thr);
        float w = sel ? ni : 0.f;
        int i = p >> 9, j = p & 511;
        tot += w;
        sx += w * (float)i;
        sy += w * (float)j;
    }
    r1[t] = tot; r2[t] = sx; r3[t] = sy;
    __syncthreads();
    for (int s = 128; s > 0; s >>= 1) {
        if (t < s) { r1[t] += r1[t + s]; r2[t] += r2[t + s]; r3[t] += r3[t + s]; }
        __syncthreads();
    }
    if (t == 0) {
        float* o = part2 + (b * NB + blk) * 4;
        o[0] = r1[0]; o[1] = r2[0]; o[2] = r3[0];
    }
}

// reduce part2 -> centroid, write stats, extract patch (dot circle / adj)
__global__ __launch_bounds__(256) void k_extract(
        const float* __restrict__ img, const float* __restrict__ part2,
        const float* __restrict__ adj, float* __restrict__ patch,
        float* __restrict__ stats) {
    int b = blockIdx.x;
    int t = threadIdx.x;
    __shared__ float r1[256], r2[256], r3[256];
    const float* pp2 = part2 + (size_t)b * NB * 4;
    r1[t] = pp2[t * 4 + 0];
    r2[t] = pp2[t * 4 + 1];
    r3[t] = pp2[t * 4 + 2];
    __syncthreads();
    for (int s = 128; s > 0; s >>= 1) {
        if (t < s) { r1[t] += r1[t + s]; r2[t] += r2[t + s]; r3[t] += r3[t + s]; }
        __syncthreads();
    }
    float tot = r1[0] + 1e-8f;
    float cx = r2[0] / tot;
    float cy = r3[0] / tot;
    float cxf = fminf(fmaxf(rintf(cx), (float)RAD), (float)(UPD - RAD));
    float cyf = fminf(fmaxf(rintf(cy), (float)RAD), (float)(UPD - RAD));
    if (t == 0) { stats[b * 8 + 2] = cxf; stats[b * 8 + 3] = cyf; }
    int cxi = (int)cxf, cyi = (int)cyf;

    float a = adj[b];
    const float* im = img + (size_t)b * (UPD * UPD);
    float* pp = patch + b * PATCHD * PATCHD;
    for (int p = t; p < PATCHD * PATCHD; p += 256) {
        int i = p / PATCHD, j = p - i * PATCHD;
        float v = im[(cxi - RAD + i) * UPD + (cyi - RAD + j)];
        int di = i - RAD, dj = j - RAD;
        if (di * di + dj * dj <= 100) v /= a;  // _DOT = 10
        pp[p] = v;
    }
}

__global__ void k_apply(const float* __restrict__ patch, const float* __restrict__ stats,
                        const float* __restrict__ theta, float* __restrict__ img) {
    int b = blockIdx.x;
    int cxi = (int)stats[b * 8 + 2], cyi = (int)stats[b * 8 + 3];
    const float* th = theta + b * 6;
    const float* pp = patch + b * PATCHD * PATCHD;
    float* im = img + (size_t)b * (UPD * UPD);
    for (int p = threadIdx.x; p < PATCHD * PATCHD; p += blockDim.x) {
        int i = p / PATCHD, j = p - i * PATCHD;
        float X = ((float)j + 0.5f) * (2.f / PATCHD) - 1.f;
        float Y = ((float)i + 0.5f) * (2.f / PATCHD) - 1.f;
        float gx = th[0] * X + th[1] * Y + th[2];
        float gy = th[3] * X + th[4] * Y + th[5];
        float v = bsample(pp, PATCHD, PATCHD, gx, gy);
        im[(cxi - RAD + i) * UPD + (cyi - RAD + j)] = v;
    }
}

// ---------------- launch ----------------

extern "C" void kernel_launch(void* const* d_in, const int* in_sizes, int n_in,
                              void* d_out, int out_size, void* d_ws, size_t ws_size,
                              hipStream_t stream) {
    const float* x = (const float*)d_in[0];
    const float* k_out = (const float*)d_in[1];
    const float* W_dec = (const float*)d_in[2];
    const float* ss = (const float*)d_in[3];
    const float* rot = (const float*)d_in[4];
    const float* masks = (const float*)d_in[5];
    const float* adj = (const float*)d_in[6];

    float* out = (float*)d_out;
    const size_t NX = (size_t)BD * H0D * H0D;      // 1,048,576
    const size_t P = (size_t)BD * UPD * UPD;       // 4,194,304
    float* out_x = out;
    float* out_base = out + NX;
    float* out_img = out + NX + P;

    float* ws = (float*)d_ws;
    float* slotA = ws;                   // pred_rot / rm1          (P floats)
    float* slotB = ws + P;               // pred_in (persistent)    (P floats)
    float* slotC = ws + 2 * P;           // base (P/4 floats) / rm (P bytes)
    unsigned char* rm = (unsigned char*)slotC;
    float* invbuf = ws + 2 * P + P / 4;  // 192 floats
    float* stats = invbuf + 192;         // 128 floats
    float* patch = stats + 128;          // 16*120*120 floats
    float* part1 = patch + BD * PATCHD * PATCHD;  // 16*256*2 floats
    float* part2 = part1 + BD * NB * 2;           // 16*256*4 floats

    hipMemcpyAsync(out_x, x, NX * sizeof(float), hipMemcpyDeviceToDevice, stream);

    k_inv<<<1, 64, 0, stream>>>(ss, rot, invbuf);
    float* inv1 = invbuf;
    float* inv2 = invbuf + 96;

    k_gemm<<<(H0D * H0D) / 256, 256, 0, stream>>>(k_out, W_dec, slotC);
    k_resize<<<(int)(P / 256), 256, 0, stream>>>(slotC, out_base);

    k_sample<<<(int)(P / 256), 256, 0, stream>>>(out_base, (size_t)(UPD * UPD), inv2,
                                                 slotA, nullptr);
    k_sample<<<(int)(P / 256), 256, 0, stream>>>(slotA, (size_t)(UPD * UPD), inv1,
                                                 slotB, out_img);

    for (int j = 0; j < 4; j++) {
        k_sample<<<(int)(P / 256), 256, 0, stream>>>(masks + (size_t)j * (UPD * UPD),
                                                     (size_t)0, inv2, slotA, nullptr);
        k_sample_thresh_stats<<<BD * NB, 256, 0, stream>>>(slotA, inv1, slotB, rm, part1);
        k_stats2p<<<BD * NB, 256, 0, stream>>>(slotB, rm, part1, part2);
        k_extract<<<BD, 256, 0, stream>>>(out_img, part2, adj, patch, stats);
        k_apply<<<BD, 256, 0, stream>>>(patch, stats, inv1, out_img);
    }
}

// Round 3
// 339.435 us; speedup vs baseline: 2.5444x; 1.1678x over previous
//
#include <hip/hip_runtime.h>

#define BD 16
#define EMBD 128
#define H0D 256
#define UPD 512
#define RAD 60
#define PATCHD 120
#define COEFF 1.5f
#define NB 256          // partial-reduction blocks per batch
#define CHUNK 1024      // pixels per partial block (262144 / 256)

// ---------------- small helpers ----------------

__device__ __forceinline__ float bsample(const float* __restrict__ img, int H, int W,
                                         float gx, float gy) {
    float xs = ((gx + 1.f) * (float)W - 1.f) * 0.5f;
    float ys = ((gy + 1.f) * (float)H - 1.f) * 0.5f;
    float x0f = floorf(xs), y0f = floorf(ys);
    float wx = xs - x0f, wy = ys - y0f;
    int x0 = (int)x0f, y0 = (int)y0f;
    bool vx0 = (x0 >= 0) && (x0 <= W - 1);
    bool vx1 = (x0 + 1 >= 0) && (x0 + 1 <= W - 1);
    bool vy0 = (y0 >= 0) && (y0 <= H - 1);
    bool vy1 = (y0 + 1 >= 0) && (y0 + 1 <= H - 1);
    int xi0 = min(max(x0, 0), W - 1);
    int xi1 = min(max(x0 + 1, 0), W - 1);
    int yi0 = min(max(y0, 0), H - 1);
    int yi1 = min(max(y0 + 1, 0), H - 1);
    float v00 = (vy0 && vx0) ? img[yi0 * W + xi0] : 0.f;
    float v01 = (vy0 && vx1) ? img[yi0 * W + xi1] : 0.f;
    float v10 = (vy1 && vx0) ? img[yi1 * W + xi0] : 0.f;
    float v11 = (vy1 && vx1) ? img[yi1 * W + xi1] : 0.f;
    return v00 * (1.f - wy) * (1.f - wx) + v01 * (1.f - wy) * wx +
           v10 * wy * (1.f - wx) + v11 * wy * wx;
}

// ---------------- kernels ----------------

__global__ void k_inv(const float* __restrict__ ss, const float* __restrict__ rot,
                      float* __restrict__ invbuf) {
    int b = threadIdx.x;
    if (b < BD) {
        {
            const float* A = ss + b * 6;
            float a = A[0], bb = A[1], c = A[3], d = A[4];
            float det = a * d - bb * c;
            float* o = invbuf + b * 6;
            o[0] = d / det; o[1] = -bb / det; o[2] = 0.f;
            o[3] = -c / det; o[4] = a / det; o[5] = 0.f;
        }
        {
            const float* A = rot + b * 6;
            float a = A[0], bb = A[1], c = A[3], d = A[4];
            float det = a * d - bb * c;
            float* o = invbuf + 96 + b * 6;
            o[0] = d / det; o[1] = -bb / det; o[2] = 0.f;
            o[3] = -c / det; o[4] = a / det; o[5] = 0.f;
        }
    }
}

__global__ __launch_bounds__(256) void k_gemm(const float* __restrict__ kout,
                                              const float* __restrict__ Wd,
                                              float* __restrict__ base) {
    __shared__ float sk[BD * EMBD];
    int t = threadIdx.x;
    for (int i = t; i < BD * EMBD; i += 256) sk[i] = kout[i];
    __syncthreads();
    int n = blockIdx.x * 256 + t;
    float acc[BD];
#pragma unroll
    for (int b = 0; b < BD; b++) acc[b] = 0.f;
    for (int e = 0; e < EMBD; e++) {
        float w = Wd[(size_t)e * (H0D * H0D) + n];
#pragma unroll
        for (int b = 0; b < BD; b++) acc[b] += sk[b * EMBD + e] * w;
    }
#pragma unroll
    for (int b = 0; b < BD; b++)
        base[(size_t)b * (H0D * H0D) + n] = fmaxf(acc[b], 0.f);
}

__global__ void k_resize(const float* __restrict__ base, float* __restrict__ out) {
    int idx = blockIdx.x * blockDim.x + threadIdx.x;
    if (idx >= BD * UPD * UPD) return;
    int b = idx >> 18;
    int p = idx & (UPD * UPD - 1);
    int yo = p >> 9, xo = p & 511;
    float ysf = fminf(fmaxf(((float)yo + 0.5f) * 0.5f - 0.5f, 0.f), 255.f);
    float xsf = fminf(fmaxf(((float)xo + 0.5f) * 0.5f - 0.5f, 0.f), 255.f);
    int y0 = (int)floorf(ysf), x0 = (int)floorf(xsf);
    int y1 = min(y0 + 1, H0D - 1), x1 = min(x0 + 1, H0D - 1);
    float wy = ysf - (float)y0, wx = xsf - (float)x0;
    const float* img = base + (size_t)b * (H0D * H0D);
    float Ia = img[y0 * H0D + x0], Ib = img[y0 * H0D + x1];
    float Ic = img[y1 * H0D + x0], Id = img[y1 * H0D + x1];
    out[idx] = Ia * (1.f - wy) * (1.f - wx) + Ib * (1.f - wy) * wx +
               Ic * wy * (1.f - wx) + Id * wy * wx;
}

__global__ void k_sample(const float* __restrict__ in, size_t inBstride,
                         const float* __restrict__ theta, float* __restrict__ out,
                         float* __restrict__ out2) {
    int idx = blockIdx.x * blockDim.x + threadIdx.x;
    if (idx >= BD * UPD * UPD) return;
    int b = idx >> 18;
    int p = idx & (UPD * UPD - 1);
    int yo = p >> 9, xo = p & 511;
    const float* th = theta + b * 6;
    float X = ((float)xo + 0.5f) * (2.f / UPD) - 1.f;
    float Y = ((float)yo + 0.5f) * (2.f / UPD) - 1.f;
    float gx = th[0] * X + th[1] * Y + th[2];
    float gy = th[3] * X + th[4] * Y + th[5];
    float v = bsample(in + (size_t)b * inBstride, UPD, UPD, gx, gy);
    out[idx] = v;
    if (out2) out2[idx] = v;
}

// All 4 masks at once: rm_j = (sample(sample(mask_j, inv2), inv1) >= 0.5)
// via nested recomputation (no rm1 intermediate). Also per-block partials of
// s_new_j = sum(pred_in * rm_j), s_m_j = sum(rm_j).
__global__ __launch_bounds__(256) void k_maskA(
        const float* __restrict__ masks, const float* __restrict__ invbuf,
        const float* __restrict__ pred_in, unsigned char* __restrict__ rm,
        float* __restrict__ part1) {
    int b = blockIdx.x >> 8;
    int blk = blockIdx.x & (NB - 1);
    int t = threadIdx.x;
    const float* th1 = invbuf + b * 6;        // outer (inv1)
    const float* th2 = invbuf + 96 + b * 6;   // inner (inv2)
    float a10 = th1[0], a11 = th1[1], a12 = th1[2];
    float a13 = th1[3], a14 = th1[4], a15 = th1[5];
    float a20 = th2[0], a21 = th2[1], a22 = th2[2];
    float a23 = th2[3], a24 = th2[4], a25 = th2[5];
    const float* pi = pred_in + (size_t)b * (UPD * UPD);
    float s_new[4] = {0.f, 0.f, 0.f, 0.f};
    float s_m[4] = {0.f, 0.f, 0.f, 0.f};
    int base = blk * CHUNK;
    for (int k = 0; k < CHUNK / 256; k++) {
        int p = base + k * 256 + t;
        int yo = p >> 9, xo = p & 511;
        float X = ((float)xo + 0.5f) * (2.f / UPD) - 1.f;
        float Y = ((float)yo + 0.5f) * (2.f / UPD) - 1.f;
        float gx = a10 * X + a11 * Y + a12;
        float gy = a13 * X + a14 * Y + a15;
        float xs = ((gx + 1.f) * (float)UPD - 1.f) * 0.5f;
        float ys = ((gy + 1.f) * (float)UPD - 1.f) * 0.5f;
        float x0f = floorf(xs), y0f = floorf(ys);
        float wx = xs - x0f, wy = ys - y0f;
        int x0 = (int)x0f, y0 = (int)y0f;
        float r[4][4];  // [neighbor q][mask j]
#pragma unroll
        for (int q = 0; q < 4; q++) {
            int qy = y0 + (q >> 1), qx = x0 + (q & 1);
            bool qv = (qx >= 0) && (qx < UPD) && (qy >= 0) && (qy < UPD);
            if (qv) {
                // inner bilinear of mask_j at affine(inv2) of pixel (qy,qx)
                float Xq = ((float)qx + 0.5f) * (2.f / UPD) - 1.f;
                float Yq = ((float)qy + 0.5f) * (2.f / UPD) - 1.f;
                float g2x = a20 * Xq + a21 * Yq + a22;
                float g2y = a23 * Xq + a24 * Yq + a25;
                float xs2 = ((g2x + 1.f) * (float)UPD - 1.f) * 0.5f;
                float ys2 = ((g2y + 1.f) * (float)UPD - 1.f) * 0.5f;
                float x0f2 = floorf(xs2), y0f2 = floorf(ys2);
                float wx2 = xs2 - x0f2, wy2 = ys2 - y0f2;
                int x02 = (int)x0f2, y02 = (int)y0f2;
                bool vx0 = (x02 >= 0) && (x02 <= UPD - 1);
                bool vx1 = (x02 + 1 >= 0) && (x02 + 1 <= UPD - 1);
                bool vy0 = (y02 >= 0) && (y02 <= UPD - 1);
                bool vy1 = (y02 + 1 >= 0) && (y02 + 1 <= UPD - 1);
                int xi0 = min(max(x02, 0), UPD - 1);
                int xi1 = min(max(x02 + 1, 0), UPD - 1);
                int yi0 = min(max(y02, 0), UPD - 1);
                int yi1 = min(max(y02 + 1, 0), UPD - 1);
                int o00 = yi0 * UPD + xi0, o01 = yi0 * UPD + xi1;
                int o10 = yi1 * UPD + xi0, o11 = yi1 * UPD + xi1;
#pragma unroll
                for (int j = 0; j < 4; j++) {
                    const float* mk = masks + (size_t)j * (UPD * UPD);
                    float v00 = (vy0 && vx0) ? mk[o00] : 0.f;
                    float v01 = (vy0 && vx1) ? mk[o01] : 0.f;
                    float v10 = (vy1 && vx0) ? mk[o10] : 0.f;
                    float v11 = (vy1 && vx1) ? mk[o11] : 0.f;
                    r[q][j] = v00 * (1.f - wy2) * (1.f - wx2) + v01 * (1.f - wy2) * wx2 +
                              v10 * wy2 * (1.f - wx2) + v11 * wy2 * wx2;
                }
            } else {
#pragma unroll
                for (int j = 0; j < 4; j++) r[q][j] = 0.f;
            }
        }
        float piv = pi[p];
#pragma unroll
        for (int j = 0; j < 4; j++) {
            float v = r[0][j] * (1.f - wy) * (1.f - wx) + r[1][j] * (1.f - wy) * wx +
                      r[2][j] * wy * (1.f - wx) + r[3][j] * wy * wx;
            float mm = (v >= 0.5f) ? 1.f : 0.f;
            rm[((size_t)j * BD + b) * (UPD * UPD) + p] = (unsigned char)mm;
            s_new[j] += piv * mm;
            s_m[j] += mm;
        }
    }
    __shared__ float r1[256], r2[256];
    for (int j = 0; j < 4; j++) {
        r1[t] = s_new[j];
        r2[t] = s_m[j];
        __syncthreads();
        for (int s = 128; s > 0; s >>= 1) {
            if (t < s) { r1[t] += r1[t + s]; r2[t] += r2[t + s]; }
            __syncthreads();
        }
        if (t == 0) {
            part1[((size_t)(j * BD + b) * NB + blk) * 2 + 0] = r1[0];
            part1[((size_t)(j * BD + b) * NB + blk) * 2 + 1] = r2[0];
        }
        __syncthreads();
    }
}

// All 4 j: reduce part1 -> thr_j (redundantly per block), then centroid partials
__global__ __launch_bounds__(256) void k_maskB(
        const float* __restrict__ pred_in, const unsigned char* __restrict__ rm,
        const float* __restrict__ part1, float* __restrict__ part2) {
    int b = blockIdx.x >> 8;
    int blk = blockIdx.x & (NB - 1);
    int t = threadIdx.x;
    __shared__ float r1[256], r2[256], r3[256];
    float thr[4];
    for (int j = 0; j < 4; j++) {
        r1[t] = part1[((size_t)(j * BD + b) * NB + t) * 2 + 0];
        r2[t] = part1[((size_t)(j * BD + b) * NB + t) * 2 + 1];
        __syncthreads();
        for (int s = 128; s > 0; s >>= 1) {
            if (t < s) { r1[t] += r1[t + s]; r2[t] += r2[t + s]; }
            __syncthreads();
        }
        thr[j] = COEFF * (r1[0] / fmaxf(r2[0], 1.f));
        __syncthreads();
    }
    float tot[4] = {0.f, 0.f, 0.f, 0.f};
    float sx[4] = {0.f, 0.f, 0.f, 0.f};
    float sy[4] = {0.f, 0.f, 0.f, 0.f};
    int base = blk * CHUNK;
    const float* pi = pred_in + (size_t)b * (UPD * UPD);
    for (int k = 0; k < CHUNK / 256; k++) {
        int p = base + k * 256 + t;
        float piv = pi[p];
        float fi = (float)(p >> 9), fj = (float)(p & 511);
#pragma unroll
        for (int j = 0; j < 4; j++) {
            float mm = (float)rm[((size_t)j * BD + b) * (UPD * UPD) + p];
            float ni = piv * mm;
            bool sel = (mm > 0.f) && (ni > thr[j]);
            float w = sel ? ni : 0.f;
            tot[j] += w;
            sx[j] += w * fi;
            sy[j] += w * fj;
        }
    }
    for (int j = 0; j < 4; j++) {
        r1[t] = tot[j]; r2[t] = sx[j]; r3[t] = sy[j];
        __syncthreads();
        for (int s = 128; s > 0; s >>= 1) {
            if (t < s) { r1[t] += r1[t + s]; r2[t] += r2[t + s]; r3[t] += r3[t + s]; }
            __syncthreads();
        }
        if (t == 0) {
            float* o = part2 + ((size_t)(j * BD + b) * NB + blk) * 4;
            o[0] = r1[0]; o[1] = r2[0]; o[2] = r3[0];
        }
        __syncthreads();
    }
}

// One block per batch: finalize 4 centroids, then 4 sequential in-block
// extract(LDS, dot/adj) -> resample -> write-back revise steps.
__global__ __launch_bounds__(1024) void k_revise(
        const float* __restrict__ part2, const float* __restrict__ invbuf,
        const float* __restrict__ adj, float* __restrict__ img) {
    int b = blockIdx.x;
    int t = threadIdx.x;
    __shared__ float patch[PATCHD * PATCHD];
    __shared__ float red[3][256];
    __shared__ int cshare[8];
    const float* th = invbuf + b * 6;  // inv1
    float th0 = th[0], th1v = th[1], th2v = th[2];
    float th3v = th[3], th4v = th[4], th5v = th[5];
    float a = adj[b];
    for (int j = 0; j < 4; j++) {
        if (t < 256) {
            const float* pp2 = part2 + ((size_t)(j * BD + b) * NB + t) * 4;
            red[0][t] = pp2[0]; red[1][t] = pp2[1]; red[2][t] = pp2[2];
        }
        __syncthreads();
        for (int s = 128; s > 0; s >>= 1) {
            if (t < s) {
                red[0][t] += red[0][t + s];
                red[1][t] += red[1][t + s];
                red[2][t] += red[2][t + s];
            }
            __syncthreads();
        }
        if (t == 0) {
            float tot = red[0][0] + 1e-8f;
            float cx = red[1][0] / tot;
            float cy = red[2][0] / tot;
            cshare[j * 2 + 0] =
                (int)fminf(fmaxf(rintf(cx), (float)RAD), (float)(UPD - RAD));
            cshare[j * 2 + 1] =
                (int)fminf(fmaxf(rintf(cy), (float)RAD), (float)(UPD - RAD));
        }
        __syncthreads();
    }
    float* im = img + (size_t)b * (UPD * UPD);
    for (int j = 0; j < 4; j++) {
        int cxi = cshare[j * 2 + 0], cyi = cshare[j * 2 + 1];
        for (int p = t; p < PATCHD * PATCHD; p += 1024) {
            int i = p / PATCHD, jj = p - i * PATCHD;
            float v = im[(cxi - RAD + i) * UPD + (cyi - RAD + jj)];
            int di = i - RAD, dj = jj - RAD;
            if (di * di + dj * dj <= 100) v /= a;  // _DOT = 10
            patch[p] = v;
        }
        __syncthreads();
        for (int p = t; p < PATCHD * PATCHD; p += 1024) {
            int i = p / PATCHD, jj = p - i * PATCHD;
            float X = ((float)jj + 0.5f) * (2.f / PATCHD) - 1.f;
            float Y = ((float)i + 0.5f) * (2.f / PATCHD) - 1.f;
            float gx = th0 * X + th1v * Y + th2v;
            float gy = th3v * X + th4v * Y + th5v;
            float v = bsample(patch, PATCHD, PATCHD, gx, gy);
            im[(cxi - RAD + i) * UPD + (cyi - RAD + jj)] = v;
        }
        __threadfence();
        __syncthreads();
    }
}

// ---------------- launch ----------------

extern "C" void kernel_launch(void* const* d_in, const int* in_sizes, int n_in,
                              void* d_out, int out_size, void* d_ws, size_t ws_size,
                              hipStream_t stream) {
    const float* x = (const float*)d_in[0];
    const float* k_out = (const float*)d_in[1];
    const float* W_dec = (const float*)d_in[2];
    const float* ss = (const float*)d_in[3];
    const float* rot = (const float*)d_in[4];
    const float* masks = (const float*)d_in[5];
    const float* adj = (const float*)d_in[6];

    float* out = (float*)d_out;
    const size_t NX = (size_t)BD * H0D * H0D;      // 1,048,576
    const size_t P = (size_t)BD * UPD * UPD;       // 4,194,304
    float* out_x = out;
    float* out_base = out + NX;
    float* out_img = out + NX + P;

    float* ws = (float*)d_ws;
    float* slotB = ws;                   // pred_in (persistent)     (P floats)
    float* slotA = ws + P;               // pred_rot / rm 4 planes   (P floats)
    unsigned char* rm = (unsigned char*)slotA;  // 4 * BD * 512*512 bytes = 4P bytes
    float* slotC = ws + 2 * P;           // base (P/4 floats)
    float* invbuf = ws + 2 * P + P / 4;  // 192 floats
    float* part1 = invbuf + 192;         // 4*16*256*2 = 32768 floats
    float* part2 = part1 + 4 * BD * NB * 2;  // 4*16*256*4 = 65536 floats

    hipMemcpyAsync(out_x, x, NX * sizeof(float), hipMemcpyDeviceToDevice, stream);

    k_inv<<<1, 64, 0, stream>>>(ss, rot, invbuf);
    float* inv1 = invbuf;
    float* inv2 = invbuf + 96;

    k_gemm<<<(H0D * H0D) / 256, 256, 0, stream>>>(k_out, W_dec, slotC);
    k_resize<<<(int)(P / 256), 256, 0, stream>>>(slotC, out_base);

    // pred_rot = sample(base_inp, inv2)
    k_sample<<<(int)(P / 256), 256, 0, stream>>>(out_base, (size_t)(UPD * UPD), inv2,
                                                 slotA, nullptr);
    // pred_in = sample(pred_rot, inv1); dual-write initial img
    k_sample<<<(int)(P / 256), 256, 0, stream>>>(slotA, (size_t)(UPD * UPD), inv1,
                                                 slotB, out_img);

    // all 4 masks: fused double-sample + threshold + stats pass 1
    k_maskA<<<BD * NB, 256, 0, stream>>>(masks, invbuf, slotB, rm, part1);
    // all 4 masks: thr + centroid partials
    k_maskB<<<BD * NB, 256, 0, stream>>>(slotB, rm, part1, part2);
    // finalize centroids + 4 sequential revise steps, one block per batch
    k_revise<<<BD, 1024, 0, stream>>>(part2, invbuf, adj, out_img);
}

// Round 4
// 218.457 us; speedup vs baseline: 3.9534x; 1.5538x over previous
//
#include <hip/hip_runtime.h>

#define BD 16
#define EMBD 128
#define H0D 256
#define UPD 512
#define RAD 60
#define PATCHD 120
#define COEFF 1.5f
#define NB 256          // partial-reduction blocks per batch
#define CHUNK 1024      // pixels per partial block (262144 / 256)

// ---------------- small helpers ----------------

__device__ __forceinline__ float bsample(const float* __restrict__ img, int H, int W,
                                         float gx, float gy) {
    float xs = ((gx + 1.f) * (float)W - 1.f) * 0.5f;
    float ys = ((gy + 1.f) * (float)H - 1.f) * 0.5f;
    float x0f = floorf(xs), y0f = floorf(ys);
    float wx = xs - x0f, wy = ys - y0f;
    int x0 = (int)x0f, y0 = (int)y0f;
    bool vx0 = (x0 >= 0) && (x0 <= W - 1);
    bool vx1 = (x0 + 1 >= 0) && (x0 + 1 <= W - 1);
    bool vy0 = (y0 >= 0) && (y0 <= H - 1);
    bool vy1 = (y0 + 1 >= 0) && (y0 + 1 <= H - 1);
    int xi0 = min(max(x0, 0), W - 1);
    int xi1 = min(max(x0 + 1, 0), W - 1);
    int yi0 = min(max(y0, 0), H - 1);
    int yi1 = min(max(y0 + 1, 0), H - 1);
    float v00 = (vy0 && vx0) ? img[yi0 * W + xi0] : 0.f;
    float v01 = (vy0 && vx1) ? img[yi0 * W + xi1] : 0.f;
    float v10 = (vy1 && vx0) ? img[yi1 * W + xi0] : 0.f;
    float v11 = (vy1 && vx1) ? img[yi1 * W + xi1] : 0.f;
    return v00 * (1.f - wy) * (1.f - wx) + v01 * (1.f - wy) * wx +
           v10 * wy * (1.f - wx) + v11 * wy * wx;
}

// ---------------- kernels ----------------

__global__ void k_inv(const float* __restrict__ ss, const float* __restrict__ rot,
                      float* __restrict__ invbuf) {
    int b = threadIdx.x;
    if (b < BD) {
        {
            const float* A = ss + b * 6;
            float a = A[0], bb = A[1], c = A[3], d = A[4];
            float det = a * d - bb * c;
            float* o = invbuf + b * 6;
            o[0] = d / det; o[1] = -bb / det; o[2] = 0.f;
            o[3] = -c / det; o[4] = a / det; o[5] = 0.f;
        }
        {
            const float* A = rot + b * 6;
            float a = A[0], bb = A[1], c = A[3], d = A[4];
            float det = a * d - bb * c;
            float* o = invbuf + 96 + b * 6;
            o[0] = d / det; o[1] = -bb / det; o[2] = 0.f;
            o[3] = -c / det; o[4] = a / det; o[5] = 0.f;
        }
    }
}

__global__ __launch_bounds__(256) void k_gemm(const float* __restrict__ kout,
                                              const float* __restrict__ Wd,
                                              float* __restrict__ base) {
    __shared__ float sk[BD * EMBD];
    int t = threadIdx.x;
    for (int i = t; i < BD * EMBD; i += 256) sk[i] = kout[i];
    __syncthreads();
    int n = blockIdx.x * 256 + t;
    float acc[BD];
#pragma unroll
    for (int b = 0; b < BD; b++) acc[b] = 0.f;
    for (int e = 0; e < EMBD; e++) {
        float w = Wd[(size_t)e * (H0D * H0D) + n];
#pragma unroll
        for (int b = 0; b < BD; b++) acc[b] += sk[b * EMBD + e] * w;
    }
#pragma unroll
    for (int b = 0; b < BD; b++)
        base[(size_t)b * (H0D * H0D) + n] = fmaxf(acc[b], 0.f);
}

__global__ void k_resize(const float* __restrict__ base, float* __restrict__ out) {
    int idx = blockIdx.x * blockDim.x + threadIdx.x;
    if (idx >= BD * UPD * UPD) return;
    int b = idx >> 18;
    int p = idx & (UPD * UPD - 1);
    int yo = p >> 9, xo = p & 511;
    float ysf = fminf(fmaxf(((float)yo + 0.5f) * 0.5f - 0.5f, 0.f), 255.f);
    float xsf = fminf(fmaxf(((float)xo + 0.5f) * 0.5f - 0.5f, 0.f), 255.f);
    int y0 = (int)floorf(ysf), x0 = (int)floorf(xsf);
    int y1 = min(y0 + 1, H0D - 1), x1 = min(x0 + 1, H0D - 1);
    float wy = ysf - (float)y0, wx = xsf - (float)x0;
    const float* img = base + (size_t)b * (H0D * H0D);
    float Ia = img[y0 * H0D + x0], Ib = img[y0 * H0D + x1];
    float Ic = img[y1 * H0D + x0], Id = img[y1 * H0D + x1];
    out[idx] = Ia * (1.f - wy) * (1.f - wx) + Ib * (1.f - wy) * wx +
               Ic * wy * (1.f - wx) + Id * wy * wx;
}

__global__ void k_sample(const float* __restrict__ in, size_t inBstride,
                         const float* __restrict__ theta, float* __restrict__ out,
                         float* __restrict__ out2) {
    int idx = blockIdx.x * blockDim.x + threadIdx.x;
    if (idx >= BD * UPD * UPD) return;
    int b = idx >> 18;
    int p = idx & (UPD * UPD - 1);
    int yo = p >> 9, xo = p & 511;
    const float* th = theta + b * 6;
    float X = ((float)xo + 0.5f) * (2.f / UPD) - 1.f;
    float Y = ((float)yo + 0.5f) * (2.f / UPD) - 1.f;
    float gx = th[0] * X + th[1] * Y + th[2];
    float gy = th[3] * X + th[4] * Y + th[5];
    float v = bsample(in + (size_t)b * inBstride, UPD, UPD, gx, gy);
    out[idx] = v;
    if (out2) out2[idx] = v;
}

// pack 4 mask planes into interleaved float4
__global__ void k_pack(const float* __restrict__ masks, float4* __restrict__ packed) {
    int p = blockIdx.x * blockDim.x + threadIdx.x;
    if (p >= UPD * UPD) return;
    float4 v;
    v.x = masks[p];
    v.y = masks[(size_t)(UPD * UPD) + p];
    v.z = masks[(size_t)2 * (UPD * UPD) + p];
    v.w = masks[(size_t)3 * (UPD * UPD) + p];
    packed[p] = v;
}

// All 4 masks at once: rm_j = (sample(sample(mask_j, inv2), inv1) >= 0.5)
// via nested recomputation over the PACKED float4 mask. Also per-block
// partials of s_new_j = sum(pred_in * rm_j), s_m_j = sum(rm_j).
__global__ __launch_bounds__(256) void k_maskA(
        const float4* __restrict__ packed, const float* __restrict__ invbuf,
        const float* __restrict__ pred_in, uchar4* __restrict__ rm,
        float* __restrict__ part1) {
    int b = blockIdx.x >> 8;
    int blk = blockIdx.x & (NB - 1);
    int t = threadIdx.x;
    const float* th1 = invbuf + b * 6;        // outer (inv1)
    const float* th2 = invbuf + 96 + b * 6;   // inner (inv2)
    float a10 = th1[0], a11 = th1[1], a12 = th1[2];
    float a13 = th1[3], a14 = th1[4], a15 = th1[5];
    float a20 = th2[0], a21 = th2[1], a22 = th2[2];
    float a23 = th2[3], a24 = th2[4], a25 = th2[5];
    const float* pi = pred_in + (size_t)b * (UPD * UPD);
    uchar4* rmb = rm + (size_t)b * (UPD * UPD);
    float s_new[4] = {0.f, 0.f, 0.f, 0.f};
    float s_m[4] = {0.f, 0.f, 0.f, 0.f};
    int base = blk * CHUNK;
    for (int k = 0; k < CHUNK / 256; k++) {
        int p = base + k * 256 + t;
        int yo = p >> 9, xo = p & 511;
        float X = ((float)xo + 0.5f) * (2.f / UPD) - 1.f;
        float Y = ((float)yo + 0.5f) * (2.f / UPD) - 1.f;
        float gx = a10 * X + a11 * Y + a12;
        float gy = a13 * X + a14 * Y + a15;
        float xs = ((gx + 1.f) * (float)UPD - 1.f) * 0.5f;
        float ys = ((gy + 1.f) * (float)UPD - 1.f) * 0.5f;
        float x0f = floorf(xs), y0f = floorf(ys);
        float wx = xs - x0f, wy = ys - y0f;
        int x0 = (int)x0f, y0 = (int)y0f;
        float r[4][4];  // [neighbor q][mask j]
#pragma unroll
        for (int q = 0; q < 4; q++) {
            int qy = y0 + (q >> 1), qx = x0 + (q & 1);
            bool qv = (qx >= 0) && (qx < UPD) && (qy >= 0) && (qy < UPD);
            if (qv) {
                float Xq = ((float)qx + 0.5f) * (2.f / UPD) - 1.f;
                float Yq = ((float)qy + 0.5f) * (2.f / UPD) - 1.f;
                float g2x = a20 * Xq + a21 * Yq + a22;
                float g2y = a23 * Xq + a24 * Yq + a25;
                float xs2 = ((g2x + 1.f) * (float)UPD - 1.f) * 0.5f;
                float ys2 = ((g2y + 1.f) * (float)UPD - 1.f) * 0.5f;
                float x0f2 = floorf(xs2), y0f2 = floorf(ys2);
                float wx2 = xs2 - x0f2, wy2 = ys2 - y0f2;
                int x02 = (int)x0f2, y02 = (int)y0f2;
                bool vx0 = (x02 >= 0) && (x02 <= UPD - 1);
                bool vx1 = (x02 + 1 >= 0) && (x02 + 1 <= UPD - 1);
                bool vy0 = (y02 >= 0) && (y02 <= UPD - 1);
                bool vy1 = (y02 + 1 >= 0) && (y02 + 1 <= UPD - 1);
                int xi0 = min(max(x02, 0), UPD - 1);
                int xi1 = min(max(x02 + 1, 0), UPD - 1);
                int yi0 = min(max(y02, 0), UPD - 1);
                int yi1 = min(max(y02 + 1, 0), UPD - 1);
                float4 m00 = packed[yi0 * UPD + xi0];
                float4 m01 = packed[yi0 * UPD + xi1];
                float4 m10 = packed[yi1 * UPD + xi0];
                float4 m11 = packed[yi1 * UPD + xi1];
                const float* f00 = (const float*)&m00;
                const float* f01 = (const float*)&m01;
                const float* f10 = (const float*)&m10;
                const float* f11 = (const float*)&m11;
#pragma unroll
                for (int j = 0; j < 4; j++) {
                    float v00 = (vy0 && vx0) ? f00[j] : 0.f;
                    float v01 = (vy0 && vx1) ? f01[j] : 0.f;
                    float v10 = (vy1 && vx0) ? f10[j] : 0.f;
                    float v11 = (vy1 && vx1) ? f11[j] : 0.f;
                    r[q][j] = v00 * (1.f - wy2) * (1.f - wx2) + v01 * (1.f - wy2) * wx2 +
                              v10 * wy2 * (1.f - wx2) + v11 * wy2 * wx2;
                }
            } else {
#pragma unroll
                for (int j = 0; j < 4; j++) r[q][j] = 0.f;
            }
        }
        float piv = pi[p];
        uchar4 rmv;
        unsigned char* rmc = (unsigned char*)&rmv;
#pragma unroll
        for (int j = 0; j < 4; j++) {
            float v = r[0][j] * (1.f - wy) * (1.f - wx) + r[1][j] * (1.f - wy) * wx +
                      r[2][j] * wy * (1.f - wx) + r[3][j] * wy * wx;
            float mm = (v >= 0.5f) ? 1.f : 0.f;
            rmc[j] = (unsigned char)mm;
            s_new[j] += piv * mm;
            s_m[j] += mm;
        }
        rmb[p] = rmv;
    }
    __shared__ float r1[256], r2[256];
    for (int j = 0; j < 4; j++) {
        r1[t] = s_new[j];
        r2[t] = s_m[j];
        __syncthreads();
        for (int s = 128; s > 0; s >>= 1) {
            if (t < s) { r1[t] += r1[t + s]; r2[t] += r2[t + s]; }
            __syncthreads();
        }
        if (t == 0) {
            part1[((size_t)(j * BD + b) * NB + blk) * 2 + 0] = r1[0];
            part1[((size_t)(j * BD + b) * NB + blk) * 2 + 1] = r2[0];
        }
        __syncthreads();
    }
}

// All 4 j: reduce part1 -> thr_j (redundantly per block), then centroid partials
__global__ __launch_bounds__(256) void k_maskB(
        const float* __restrict__ pred_in, const uchar4* __restrict__ rm,
        const float* __restrict__ part1, float* __restrict__ part2) {
    int b = blockIdx.x >> 8;
    int blk = blockIdx.x & (NB - 1);
    int t = threadIdx.x;
    __shared__ float r1[256], r2[256], r3[256];
    float thr[4];
    for (int j = 0; j < 4; j++) {
        r1[t] = part1[((size_t)(j * BD + b) * NB + t) * 2 + 0];
        r2[t] = part1[((size_t)(j * BD + b) * NB + t) * 2 + 1];
        __syncthreads();
        for (int s = 128; s > 0; s >>= 1) {
            if (t < s) { r1[t] += r1[t + s]; r2[t] += r2[t + s]; }
            __syncthreads();
        }
        thr[j] = COEFF * (r1[0] / fmaxf(r2[0], 1.f));
        __syncthreads();
    }
    float tot[4] = {0.f, 0.f, 0.f, 0.f};
    float sx[4] = {0.f, 0.f, 0.f, 0.f};
    float sy[4] = {0.f, 0.f, 0.f, 0.f};
    int base = blk * CHUNK;
    const float* pi = pred_in + (size_t)b * (UPD * UPD);
    const uchar4* rmb = rm + (size_t)b * (UPD * UPD);
    for (int k = 0; k < CHUNK / 256; k++) {
        int p = base + k * 256 + t;
        float piv = pi[p];
        float fi = (float)(p >> 9), fj = (float)(p & 511);
        uchar4 mm4 = rmb[p];
        const unsigned char* mmc = (const unsigned char*)&mm4;
#pragma unroll
        for (int j = 0; j < 4; j++) {
            float mm = (float)mmc[j];
            float ni = piv * mm;
            bool sel = (mm > 0.f) && (ni > thr[j]);
            float w = sel ? ni : 0.f;
            tot[j] += w;
            sx[j] += w * fi;
            sy[j] += w * fj;
        }
    }
    for (int j = 0; j < 4; j++) {
        r1[t] = tot[j]; r2[t] = sx[j]; r3[t] = sy[j];
        __syncthreads();
        for (int s = 128; s > 0; s >>= 1) {
            if (t < s) { r1[t] += r1[t + s]; r2[t] += r2[t + s]; r3[t] += r3[t + s]; }
            __syncthreads();
        }
        if (t == 0) {
            float* o = part2 + ((size_t)(j * BD + b) * NB + blk) * 4;
            o[0] = r1[0]; o[1] = r2[0]; o[2] = r3[0];
        }
        __syncthreads();
    }
}

// One block per batch: finalize 4 centroids, then 4 sequential in-block
// extract(LDS, dot/adj) -> resample -> write-back revise steps.
__global__ __launch_bounds__(1024) void k_revise(
        const float* __restrict__ part2, const float* __restrict__ invbuf,
        const float* __restrict__ adj, float* __restrict__ img) {
    int b = blockIdx.x;
    int t = threadIdx.x;
    __shared__ float patch[PATCHD * PATCHD];
    __shared__ float red[3][256];
    __shared__ int cshare[8];
    const float* th = invbuf + b * 6;  // inv1
    float th0 = th[0], th1v = th[1], th2v = th[2];
    float th3v = th[3], th4v = th[4], th5v = th[5];
    float a = adj[b];
    for (int j = 0; j < 4; j++) {
        if (t < 256) {
            const float* pp2 = part2 + ((size_t)(j * BD + b) * NB + t) * 4;
            red[0][t] = pp2[0]; red[1][t] = pp2[1]; red[2][t] = pp2[2];
        }
        __syncthreads();
        for (int s = 128; s > 0; s >>= 1) {
            if (t < s) {
                red[0][t] += red[0][t + s];
                red[1][t] += red[1][t + s];
                red[2][t] += red[2][t + s];
            }
            __syncthreads();
        }
        if (t == 0) {
            float tot = red[0][0] + 1e-8f;
            float cx = red[1][0] / tot;
            float cy = red[2][0] / tot;
            cshare[j * 2 + 0] =
                (int)fminf(fmaxf(rintf(cx), (float)RAD), (float)(UPD - RAD));
            cshare[j * 2 + 1] =
                (int)fminf(fmaxf(rintf(cy), (float)RAD), (float)(UPD - RAD));
        }
        __syncthreads();
    }
    float* im = img + (size_t)b * (UPD * UPD);
    for (int j = 0; j < 4; j++) {
        int cxi = cshare[j * 2 + 0], cyi = cshare[j * 2 + 1];
        for (int p = t; p < PATCHD * PATCHD; p += 1024) {
            int i = p / PATCHD, jj = p - i * PATCHD;
            float v = im[(cxi - RAD + i) * UPD + (cyi - RAD + jj)];
            int di = i - RAD, dj = jj - RAD;
            if (di * di + dj * dj <= 100) v /= a;  // _DOT = 10
            patch[p] = v;
        }
        __syncthreads();
        for (int p = t; p < PATCHD * PATCHD; p += 1024) {
            int i = p / PATCHD, jj = p - i * PATCHD;
            float X = ((float)jj + 0.5f) * (2.f / PATCHD) - 1.f;
            float Y = ((float)i + 0.5f) * (2.f / PATCHD) - 1.f;
            float gx = th0 * X + th1v * Y + th2v;
            float gy = th3v * X + th4v * Y + th5v;
            float v = bsample(patch, PATCHD, PATCHD, gx, gy);
            im[(cxi - RAD + i) * UPD + (cyi - RAD + jj)] = v;
        }
        __threadfence();
        __syncthreads();
    }
}

// ---------------- launch ----------------

extern "C" void kernel_launch(void* const* d_in, const int* in_sizes, int n_in,
                              void* d_out, int out_size, void* d_ws, size_t ws_size,
                              hipStream_t stream) {
    const float* x = (const float*)d_in[0];
    const float* k_out = (const float*)d_in[1];
    const float* W_dec = (const float*)d_in[2];
    const float* ss = (const float*)d_in[3];
    const float* rot = (const float*)d_in[4];
    const float* masks = (const float*)d_in[5];
    const float* adj = (const float*)d_in[6];

    float* out = (float*)d_out;
    const size_t NX = (size_t)BD * H0D * H0D;      // 1,048,576
    const size_t P = (size_t)BD * UPD * UPD;       // 4,194,304
    float* out_x = out;
    float* out_base = out + NX;
    float* out_img = out + NX + P;

    float* ws = (float*)d_ws;
    float* slotB = ws;                   // pred_in (persistent)     (P floats)
    float* slotA = ws + P;               // pred_rot / rm uchar4     (P floats)
    uchar4* rm = (uchar4*)slotA;         // BD*512*512 uchar4 = P bytes... (P/4 u4)
    float* slotC = ws + 2 * P;           // base (P/4 floats)
    float* invbuf = ws + 2 * P + P / 4;  // 192 floats
    float* part1 = invbuf + 192;         // 4*16*256*2 = 32768 floats
    float* part2 = part1 + 4 * BD * NB * 2;   // 4*16*256*4 = 65536 floats
    float4* packed = (float4*)(part2 + 4 * BD * NB * 4);  // 512*512 float4 = 4MB

    hipMemcpyAsync(out_x, x, NX * sizeof(float), hipMemcpyDeviceToDevice, stream);

    k_inv<<<1, 64, 0, stream>>>(ss, rot, invbuf);
    float* inv1 = invbuf;
    float* inv2 = invbuf + 96;

    k_pack<<<(UPD * UPD) / 256, 256, 0, stream>>>(masks, packed);
    k_gemm<<<(H0D * H0D) / 256, 256, 0, stream>>>(k_out, W_dec, slotC);
    k_resize<<<(int)(P / 256), 256, 0, stream>>>(slotC, out_base);

    // pred_rot = sample(base_inp, inv2)
    k_sample<<<(int)(P / 256), 256, 0, stream>>>(out_base, (size_t)(UPD * UPD), inv2,
                                                 slotA, nullptr);
    // pred_in = sample(pred_rot, inv1); dual-write initial img
    k_sample<<<(int)(P / 256), 256, 0, stream>>>(slotA, (size_t)(UPD * UPD), inv1,
                                                 slotB, out_img);

    // all 4 masks: fused double-sample + threshold + stats pass 1
    k_maskA<<<BD * NB, 256, 0, stream>>>(packed, invbuf, slotB, rm, part1);
    // all 4 masks: thr + centroid partials
    k_maskB<<<BD * NB, 256, 0, stream>>>(slotB, rm, part1, part2);
    // finalize centroids + 4 sequential revise steps, one block per batch
    k_revise<<<BD, 1024, 0, stream>>>(part2, invbuf, adj, out_img);
}

// Round 5
// 160.329 us; speedup vs baseline: 5.3867x; 1.3626x over previous
//
#include <hip/hip_runtime.h>

#define BD 16
#define EMBD 128
#define H0D 256
#define UPD 512
#define RAD 60
#define PATCHD 120
#define COEFF 1.5f
#define NB 256          // partial-reduction blocks per batch
#define CHUNK 1024      // pixels per partial block (2 rows of 512)
#define SKIPR 32.0f     // 24 (disk) + 8 margin (bilinear/floor reach <= ~3.5)

// ---------------- small helpers ----------------

__device__ __forceinline__ float bsample(const float* __restrict__ img, int H, int W,
                                         float gx, float gy) {
    float xs = ((gx + 1.f) * (float)W - 1.f) * 0.5f;
    float ys = ((gy + 1.f) * (float)H - 1.f) * 0.5f;
    float x0f = floorf(xs), y0f = floorf(ys);
    float wx = xs - x0f, wy = ys - y0f;
    int x0 = (int)x0f, y0 = (int)y0f;
    bool vx0 = (x0 >= 0) && (x0 <= W - 1);
    bool vx1 = (x0 + 1 >= 0) && (x0 + 1 <= W - 1);
    bool vy0 = (y0 >= 0) && (y0 <= H - 1);
    bool vy1 = (y0 + 1 >= 0) && (y0 + 1 <= H - 1);
    int xi0 = min(max(x0, 0), W - 1);
    int xi1 = min(max(x0 + 1, 0), W - 1);
    int yi0 = min(max(y0, 0), H - 1);
    int yi1 = min(max(y0 + 1, 0), H - 1);
    float v00 = (vy0 && vx0) ? img[yi0 * W + xi0] : 0.f;
    float v01 = (vy0 && vx1) ? img[yi0 * W + xi1] : 0.f;
    float v10 = (vy1 && vx0) ? img[yi1 * W + xi0] : 0.f;
    float v11 = (vy1 && vx1) ? img[yi1 * W + xi1] : 0.f;
    return v00 * (1.f - wy) * (1.f - wx) + v01 * (1.f - wy) * wx +
           v10 * wy * (1.f - wx) + v11 * wy * wx;
}

// ---------------- kernels ----------------

__global__ void k_inv(const float* __restrict__ ss, const float* __restrict__ rot,
                      float* __restrict__ invbuf) {
    int b = threadIdx.x;
    if (b < BD) {
        {
            const float* A = ss + b * 6;
            float a = A[0], bb = A[1], c = A[3], d = A[4];
            float det = a * d - bb * c;
            float* o = invbuf + b * 6;
            o[0] = d / det; o[1] = -bb / det; o[2] = 0.f;
            o[3] = -c / det; o[4] = a / det; o[5] = 0.f;
        }
        {
            const float* A = rot + b * 6;
            float a = A[0], bb = A[1], c = A[3], d = A[4];
            float det = a * d - bb * c;
            float* o = invbuf + 96 + b * 6;
            o[0] = d / det; o[1] = -bb / det; o[2] = 0.f;
            o[3] = -c / det; o[4] = a / det; o[5] = 0.f;
        }
    }
}

__global__ __launch_bounds__(256) void k_gemm(const float* __restrict__ kout,
                                              const float* __restrict__ Wd,
                                              float* __restrict__ base) {
    __shared__ float sk[BD * EMBD];
    int t = threadIdx.x;
    for (int i = t; i < BD * EMBD; i += 256) sk[i] = kout[i];
    __syncthreads();
    int n = blockIdx.x * 256 + t;
    float acc[BD];
#pragma unroll
    for (int b = 0; b < BD; b++) acc[b] = 0.f;
    for (int e = 0; e < EMBD; e++) {
        float w = Wd[(size_t)e * (H0D * H0D) + n];
#pragma unroll
        for (int b = 0; b < BD; b++) acc[b] += sk[b * EMBD + e] * w;
    }
#pragma unroll
    for (int b = 0; b < BD; b++)
        base[(size_t)b * (H0D * H0D) + n] = fmaxf(acc[b], 0.f);
}

__global__ void k_resize(const float* __restrict__ base, float* __restrict__ out) {
    int idx = blockIdx.x * blockDim.x + threadIdx.x;
    if (idx >= BD * UPD * UPD) return;
    int b = idx >> 18;
    int p = idx & (UPD * UPD - 1);
    int yo = p >> 9, xo = p & 511;
    float ysf = fminf(fmaxf(((float)yo + 0.5f) * 0.5f - 0.5f, 0.f), 255.f);
    float xsf = fminf(fmaxf(((float)xo + 0.5f) * 0.5f - 0.5f, 0.f), 255.f);
    int y0 = (int)floorf(ysf), x0 = (int)floorf(xsf);
    int y1 = min(y0 + 1, H0D - 1), x1 = min(x0 + 1, H0D - 1);
    float wy = ysf - (float)y0, wx = xsf - (float)x0;
    const float* img = base + (size_t)b * (H0D * H0D);
    float Ia = img[y0 * H0D + x0], Ib = img[y0 * H0D + x1];
    float Ic = img[y1 * H0D + x0], Id = img[y1 * H0D + x1];
    out[idx] = Ia * (1.f - wy) * (1.f - wx) + Ib * (1.f - wy) * wx +
               Ic * wy * (1.f - wx) + Id * wy * wx;
}

// fused pred_in = sample(sample(base_inp, inv2), inv1), nested recompute.
// writes pred_in to both slotB and out_img (bit-identical to chained version).
__global__ __launch_bounds__(256) void k_pred(
        const float* __restrict__ base_inp, const float* __restrict__ invbuf,
        float* __restrict__ pred_in, float* __restrict__ out_img) {
    int idx = blockIdx.x * blockDim.x + threadIdx.x;
    if (idx >= BD * UPD * UPD) return;
    int b = idx >> 18;
    int p = idx & (UPD * UPD - 1);
    int yo = p >> 9, xo = p & 511;
    const float* th1 = invbuf + b * 6;        // outer (inv1)
    const float* th2 = invbuf + 96 + b * 6;   // inner (inv2)
    float a10 = th1[0], a11 = th1[1], a12 = th1[2];
    float a13 = th1[3], a14 = th1[4], a15 = th1[5];
    float a20 = th2[0], a21 = th2[1], a22 = th2[2];
    float a23 = th2[3], a24 = th2[4], a25 = th2[5];
    const float* img = base_inp + (size_t)b * (UPD * UPD);
    float X = ((float)xo + 0.5f) * (2.f / UPD) - 1.f;
    float Y = ((float)yo + 0.5f) * (2.f / UPD) - 1.f;
    float gx = a10 * X + a11 * Y + a12;
    float gy = a13 * X + a14 * Y + a15;
    float xs = ((gx + 1.f) * (float)UPD - 1.f) * 0.5f;
    float ys = ((gy + 1.f) * (float)UPD - 1.f) * 0.5f;
    float x0f = floorf(xs), y0f = floorf(ys);
    float wx = xs - x0f, wy = ys - y0f;
    int x0 = (int)x0f, y0 = (int)y0f;
    float r[4];
#pragma unroll
    for (int q = 0; q < 4; q++) {
        int qy = y0 + (q >> 1), qx = x0 + (q & 1);
        bool qv = (qx >= 0) && (qx < UPD) && (qy >= 0) && (qy < UPD);
        if (qv) {
            float Xq = ((float)qx + 0.5f) * (2.f / UPD) - 1.f;
            float Yq = ((float)qy + 0.5f) * (2.f / UPD) - 1.f;
            float g2x = a20 * Xq + a21 * Yq + a22;
            float g2y = a23 * Xq + a24 * Yq + a25;
            r[q] = bsample(img, UPD, UPD, g2x, g2y);
        } else {
            r[q] = 0.f;
        }
    }
    float v = r[0] * (1.f - wy) * (1.f - wx) + r[1] * (1.f - wy) * wx +
              r[2] * wy * (1.f - wx) + r[3] * wy * wx;
    pred_in[idx] = v;
    out_img[idx] = v;
}

// pack 4 mask planes into interleaved float4
__global__ void k_pack(const float* __restrict__ masks, float4* __restrict__ packed) {
    int p = blockIdx.x * blockDim.x + threadIdx.x;
    if (p >= UPD * UPD) return;
    float4 v;
    v.x = masks[p];
    v.y = masks[(size_t)(UPD * UPD) + p];
    v.z = masks[(size_t)2 * (UPD * UPD) + p];
    v.w = masks[(size_t)3 * (UPD * UPD) + p];
    packed[p] = v;
}

// All 4 masks: rm_j = (sample(sample(mask_j, inv2), inv1) >= 0.5) with
// analytic strip-skip (composite affine segment vs disk centers).
__global__ __launch_bounds__(256) void k_maskA(
        const float4* __restrict__ packed, const float* __restrict__ invbuf,
        const float* __restrict__ pred_in, uchar4* __restrict__ rm,
        float* __restrict__ part1, unsigned int* __restrict__ flags) {
    int b = blockIdx.x >> 8;
    int blk = blockIdx.x & (NB - 1);
    int t = threadIdx.x;
    const float* th1 = invbuf + b * 6;        // outer (inv1)
    const float* th2 = invbuf + 96 + b * 6;   // inner (inv2)
    float a10 = th1[0], a11 = th1[1], a12 = th1[2];
    float a13 = th1[3], a14 = th1[4], a15 = th1[5];
    float a20 = th2[0], a21 = th2[1], a22 = th2[2];
    float a23 = th2[3], a24 = th2[4], a25 = th2[5];

    __shared__ unsigned int sflag;
    if (t == 0) {
        const float crow[4] = {160.f, 160.f, 352.f, 352.f};
        const float ccol[4] = {160.f, 352.f, 160.f, 352.f};
        unsigned int f = 0;
        int r0 = blk * 2;
        for (int rr = 0; rr < 2; rr++) {
            float Y = ((float)(r0 + rr) + 0.5f) * (2.f / UPD) - 1.f;
            float X0 = 0.5f * (2.f / UPD) - 1.f;
            float X1 = 511.5f * (2.f / UPD) - 1.f;
            float gx0 = a10 * X0 + a11 * Y + a12, gy0 = a13 * X0 + a14 * Y + a15;
            float gx1 = a10 * X1 + a11 * Y + a12, gy1 = a13 * X1 + a14 * Y + a15;
            float c0 = 256.f * (a20 * gx0 + a21 * gy0 + a22) + 255.5f;
            float w0 = 256.f * (a23 * gx0 + a24 * gy0 + a25) + 255.5f;
            float c1 = 256.f * (a20 * gx1 + a21 * gy1 + a22) + 255.5f;
            float w1 = 256.f * (a23 * gx1 + a24 * gy1 + a25) + 255.5f;
            float vx = c1 - c0, vy = w1 - w0;
            float vv = fmaxf(vx * vx + vy * vy, 1e-12f);
            for (int j = 0; j < 4; j++) {
                float ux = c0 - ccol[j], uy = w0 - crow[j];
                float tt = fminf(fmaxf(-(ux * vx + uy * vy) / vv, 0.f), 1.f);
                float dx = ux + tt * vx, dy = uy + tt * vy;
                if (dx * dx + dy * dy <= SKIPR * SKIPR) f |= (1u << j);
            }
        }
        sflag = f;
        flags[b * NB + blk] = f;
    }
    __syncthreads();
    if (sflag == 0) {
        if (t == 0) {
#pragma unroll
            for (int j = 0; j < 4; j++) {
                part1[((size_t)(j * BD + b) * NB + blk) * 2 + 0] = 0.f;
                part1[((size_t)(j * BD + b) * NB + blk) * 2 + 1] = 0.f;
            }
        }
        return;
    }

    const float* pi = pred_in + (size_t)b * (UPD * UPD);
    uchar4* rmb = rm + (size_t)b * (UPD * UPD);
    float s_new[4] = {0.f, 0.f, 0.f, 0.f};
    float s_m[4] = {0.f, 0.f, 0.f, 0.f};
    int base = blk * CHUNK;
    for (int k = 0; k < CHUNK / 256; k++) {
        int p = base + k * 256 + t;
        int yo = p >> 9, xo = p & 511;
        float X = ((float)xo + 0.5f) * (2.f / UPD) - 1.f;
        float Y = ((float)yo + 0.5f) * (2.f / UPD) - 1.f;
        float gx = a10 * X + a11 * Y + a12;
        float gy = a13 * X + a14 * Y + a15;
        float xs = ((gx + 1.f) * (float)UPD - 1.f) * 0.5f;
        float ys = ((gy + 1.f) * (float)UPD - 1.f) * 0.5f;
        float x0f = floorf(xs), y0f = floorf(ys);
        float wx = xs - x0f, wy = ys - y0f;
        int x0 = (int)x0f, y0 = (int)y0f;
        float r[4][4];  // [neighbor q][mask j]
#pragma unroll
        for (int q = 0; q < 4; q++) {
            int qy = y0 + (q >> 1), qx = x0 + (q & 1);
            bool qv = (qx >= 0) && (qx < UPD) && (qy >= 0) && (qy < UPD);
            if (qv) {
                float Xq = ((float)qx + 0.5f) * (2.f / UPD) - 1.f;
                float Yq = ((float)qy + 0.5f) * (2.f / UPD) - 1.f;
                float g2x = a20 * Xq + a21 * Yq + a22;
                float g2y = a23 * Xq + a24 * Yq + a25;
                float xs2 = ((g2x + 1.f) * (float)UPD - 1.f) * 0.5f;
                float ys2 = ((g2y + 1.f) * (float)UPD - 1.f) * 0.5f;
                float x0f2 = floorf(xs2), y0f2 = floorf(ys2);
                float wx2 = xs2 - x0f2, wy2 = ys2 - y0f2;
                int x02 = (int)x0f2, y02 = (int)y0f2;
                bool vx0 = (x02 >= 0) && (x02 <= UPD - 1);
                bool vx1 = (x02 + 1 >= 0) && (x02 + 1 <= UPD - 1);
                bool vy0 = (y02 >= 0) && (y02 <= UPD - 1);
                bool vy1 = (y02 + 1 >= 0) && (y02 + 1 <= UPD - 1);
                int xi0 = min(max(x02, 0), UPD - 1);
                int xi1 = min(max(x02 + 1, 0), UPD - 1);
                int yi0 = min(max(y02, 0), UPD - 1);
                int yi1 = min(max(y02 + 1, 0), UPD - 1);
                float4 m00 = packed[yi0 * UPD + xi0];
                float4 m01 = packed[yi0 * UPD + xi1];
                float4 m10 = packed[yi1 * UPD + xi0];
                float4 m11 = packed[yi1 * UPD + xi1];
                const float* f00 = (const float*)&m00;
                const float* f01 = (const float*)&m01;
                const float* f10 = (const float*)&m10;
                const float* f11 = (const float*)&m11;
#pragma unroll
                for (int j = 0; j < 4; j++) {
                    float v00 = (vy0 && vx0) ? f00[j] : 0.f;
                    float v01 = (vy0 && vx1) ? f01[j] : 0.f;
                    float v10 = (vy1 && vx0) ? f10[j] : 0.f;
                    float v11 = (vy1 && vx1) ? f11[j] : 0.f;
                    r[q][j] = v00 * (1.f - wy2) * (1.f - wx2) + v01 * (1.f - wy2) * wx2 +
                              v10 * wy2 * (1.f - wx2) + v11 * wy2 * wx2;
                }
            } else {
#pragma unroll
                for (int j = 0; j < 4; j++) r[q][j] = 0.f;
            }
        }
        float piv = pi[p];
        uchar4 rmv;
        unsigned char* rmc = (unsigned char*)&rmv;
#pragma unroll
        for (int j = 0; j < 4; j++) {
            float v = r[0][j] * (1.f - wy) * (1.f - wx) + r[1][j] * (1.f - wy) * wx +
                      r[2][j] * wy * (1.f - wx) + r[3][j] * wy * wx;
            float mm = (v >= 0.5f) ? 1.f : 0.f;
            rmc[j] = (unsigned char)mm;
            s_new[j] += piv * mm;
            s_m[j] += mm;
        }
        rmb[p] = rmv;
    }
    __shared__ float r1[256], r2[256];
    for (int j = 0; j < 4; j++) {
        r1[t] = s_new[j];
        r2[t] = s_m[j];
        __syncthreads();
        for (int s = 128; s > 0; s >>= 1) {
            if (t < s) { r1[t] += r1[t + s]; r2[t] += r2[t + s]; }
            __syncthreads();
        }
        if (t == 0) {
            part1[((size_t)(j * BD + b) * NB + blk) * 2 + 0] = r1[0];
            part1[((size_t)(j * BD + b) * NB + blk) * 2 + 1] = r2[0];
        }
        __syncthreads();
    }
}

// All 4 j: thr (redundant reduce of part1) + centroid partials; strip-skip via flags
__global__ __launch_bounds__(256) void k_maskB(
        const float* __restrict__ pred_in, const uchar4* __restrict__ rm,
        const float* __restrict__ part1, float* __restrict__ part2,
        const unsigned int* __restrict__ flags) {
    int b = blockIdx.x >> 8;
    int blk = blockIdx.x & (NB - 1);
    int t = threadIdx.x;
    unsigned int flag = flags[b * NB + blk];
    if (flag == 0) {
        if (t == 0) {
#pragma unroll
            for (int j = 0; j < 4; j++) {
                float* o = part2 + ((size_t)(j * BD + b) * NB + blk) * 4;
                o[0] = 0.f; o[1] = 0.f; o[2] = 0.f;
            }
        }
        return;
    }
    __shared__ float r1[256], r2[256], r3[256];
    float thr[4];
    for (int j = 0; j < 4; j++) {
        r1[t] = part1[((size_t)(j * BD + b) * NB + t) * 2 + 0];
        r2[t] = part1[((size_t)(j * BD + b) * NB + t) * 2 + 1];
        __syncthreads();
        for (int s = 128; s > 0; s >>= 1) {
            if (t < s) { r1[t] += r1[t + s]; r2[t] += r2[t + s]; }
            __syncthreads();
        }
        thr[j] = COEFF * (r1[0] / fmaxf(r2[0], 1.f));
        __syncthreads();
    }
    float tot[4] = {0.f, 0.f, 0.f, 0.f};
    float sx[4] = {0.f, 0.f, 0.f, 0.f};
    float sy[4] = {0.f, 0.f, 0.f, 0.f};
    int base = blk * CHUNK;
    const float* pi = pred_in + (size_t)b * (UPD * UPD);
    const uchar4* rmb = rm + (size_t)b * (UPD * UPD);
    for (int k = 0; k < CHUNK / 256; k++) {
        int p = base + k * 256 + t;
        uchar4 mm4 = rmb[p];
        unsigned int mmbits;
        __builtin_memcpy(&mmbits, &mm4, 4);
        if (mmbits == 0) continue;
        float piv = pi[p];
        float fi = (float)(p >> 9), fj = (float)(p & 511);
        const unsigned char* mmc = (const unsigned char*)&mm4;
#pragma unroll
        for (int j = 0; j < 4; j++) {
            float mm = (float)mmc[j];
            float ni = piv * mm;
            bool sel = (mm > 0.f) && (ni > thr[j]);
            float w = sel ? ni : 0.f;
            tot[j] += w;
            sx[j] += w * fi;
            sy[j] += w * fj;
        }
    }
    for (int j = 0; j < 4; j++) {
        r1[t] = tot[j]; r2[t] = sx[j]; r3[t] = sy[j];
        __syncthreads();
        for (int s = 128; s > 0; s >>= 1) {
            if (t < s) { r1[t] += r1[t + s]; r2[t] += r2[t + s]; r3[t] += r3[t + s]; }
            __syncthreads();
        }
        if (t == 0) {
            float* o = part2 + ((size_t)(j * BD + b) * NB + blk) * 4;
            o[0] = r1[0]; o[1] = r2[0]; o[2] = r3[0];
        }
        __syncthreads();
    }
}

// 64 blocks = (b, j). Each block reduces all 4 centroids; if patches are
// pairwise disjoint (the near-rigid-warp common case), each block revises its
// own j concurrently (disjoint pixels). Otherwise block j==0 does the exact
// sequential 4-step path.
__global__ __launch_bounds__(1024) void k_revise(
        const float* __restrict__ part2, const float* __restrict__ invbuf,
        const float* __restrict__ adj, float* __restrict__ img) {
    int b = blockIdx.x >> 2;
    int jown = blockIdx.x & 3;
    int t = threadIdx.x;
    __shared__ float patch[PATCHD * PATCHD];
    __shared__ float red[3][256];
    __shared__ int cshare[8];
    for (int j = 0; j < 4; j++) {
        if (t < 256) {
            const float* pp2 = part2 + ((size_t)(j * BD + b) * NB + t) * 4;
            red[0][t] = pp2[0]; red[1][t] = pp2[1]; red[2][t] = pp2[2];
        }
        __syncthreads();
        for (int s = 128; s > 0; s >>= 1) {
            if (t < s) {
                red[0][t] += red[0][t + s];
                red[1][t] += red[1][t + s];
                red[2][t] += red[2][t + s];
            }
            __syncthreads();
        }
        if (t == 0) {
            float tot = red[0][0] + 1e-8f;
            float cx = red[1][0] / tot;
            float cy = red[2][0] / tot;
            cshare[j * 2 + 0] =
                (int)fminf(fmaxf(rintf(cx), (float)RAD), (float)(UPD - RAD));
            cshare[j * 2 + 1] =
                (int)fminf(fmaxf(rintf(cy), (float)RAD), (float)(UPD - RAD));
        }
        __syncthreads();
    }
    bool overlap = false;
#pragma unroll
    for (int a = 0; a < 4; a++)
#pragma unroll
        for (int c = a + 1; c < 4; c++) {
            int dr = cshare[a * 2] - cshare[c * 2];
            int dc = cshare[a * 2 + 1] - cshare[c * 2 + 1];
            if (dr < 0) dr = -dr;
            if (dc < 0) dc = -dc;
            if (dr < 2 * RAD && dc < 2 * RAD) overlap = true;
        }

    const float* th = invbuf + b * 6;  // inv1
    float th0 = th[0], th1v = th[1], th2v = th[2];
    float th3v = th[3], th4v = th[4], th5v = th[5];
    float a = adj[b];
    float* im = img + (size_t)b * (UPD * UPD);

    int jlo = jown, jhi = jown + 1;
    if (overlap) {
        if (jown != 0) return;
        jlo = 0; jhi = 4;
    }
    for (int j = jlo; j < jhi; j++) {
        int cxi = cshare[j * 2 + 0], cyi = cshare[j * 2 + 1];
        for (int p = t; p < PATCHD * PATCHD; p += 1024) {
            int i = p / PATCHD, jj = p - i * PATCHD;
            float v = im[(cxi - RAD + i) * UPD + (cyi - RAD + jj)];
            int di = i - RAD, dj = jj - RAD;
            if (di * di + dj * dj <= 100) v /= a;  // _DOT = 10
            patch[p] = v;
        }
        __syncthreads();
        for (int p = t; p < PATCHD * PATCHD; p += 1024) {
            int i = p / PATCHD, jj = p - i * PATCHD;
            float X = ((float)jj + 0.5f) * (2.f / PATCHD) - 1.f;
            float Y = ((float)i + 0.5f) * (2.f / PATCHD) - 1.f;
            float gx = th0 * X + th1v * Y + th2v;
            float gy = th3v * X + th4v * Y + th5v;
            float v = bsample(patch, PATCHD, PATCHD, gx, gy);
            im[(cxi - RAD + i) * UPD + (cyi - RAD + jj)] = v;
        }
        __syncthreads();
    }
}

// ---------------- launch ----------------

extern "C" void kernel_launch(void* const* d_in, const int* in_sizes, int n_in,
                              void* d_out, int out_size, void* d_ws, size_t ws_size,
                              hipStream_t stream) {
    const float* x = (const float*)d_in[0];
    const float* k_out = (const float*)d_in[1];
    const float* W_dec = (const float*)d_in[2];
    const float* ss = (const float*)d_in[3];
    const float* rot = (const float*)d_in[4];
    const float* masks = (const float*)d_in[5];
    const float* adj = (const float*)d_in[6];

    float* out = (float*)d_out;
    const size_t NX = (size_t)BD * H0D * H0D;      // 1,048,576
    const size_t P = (size_t)BD * UPD * UPD;       // 4,194,304
    float* out_x = out;
    float* out_base = out + NX;
    float* out_img = out + NX + P;

    float* ws = (float*)d_ws;
    float* slotB = ws;                   // pred_in (persistent)  (P floats)
    uchar4* rm = (uchar4*)(ws + P);      // BD*512*512 uchar4     (P floats space)
    float* slotC = ws + 2 * P;           // base (P/4 floats)
    float* invbuf = ws + 2 * P + P / 4;  // 192 floats
    float* part1 = invbuf + 192;                  // 4*16*256*2 floats
    float* part2 = part1 + 4 * BD * NB * 2;       // 4*16*256*4 floats
    unsigned int* flags = (unsigned int*)(part2 + 4 * BD * NB * 4);  // 16*256 uints
    float4* packed = (float4*)(flags + BD * NB);  // 512*512 float4 = 4MB

    hipMemcpyAsync(out_x, x, NX * sizeof(float), hipMemcpyDeviceToDevice, stream);

    k_inv<<<1, 64, 0, stream>>>(ss, rot, invbuf);
    k_pack<<<(UPD * UPD) / 256, 256, 0, stream>>>(masks, packed);
    k_gemm<<<(H0D * H0D) / 256, 256, 0, stream>>>(k_out, W_dec, slotC);
    k_resize<<<(int)(P / 256), 256, 0, stream>>>(slotC, out_base);

    // pred_in = sample(sample(base_inp, inv2), inv1); dual-write initial img
    k_pred<<<(int)(P / 256), 256, 0, stream>>>(out_base, invbuf, slotB, out_img);

    // all 4 masks: fused double-sample + threshold + stats pass 1 (+ strip skip)
    k_maskA<<<BD * NB, 256, 0, stream>>>(packed, invbuf, slotB, rm, part1, flags);
    // all 4 masks: thr + centroid partials
    k_maskB<<<BD * NB, 256, 0, stream>>>(slotB, rm, part1, part2, flags);
    // centroids + revise, parallel over (b, j) with sequential fallback
    k_revise<<<BD * 4, 1024, 0, stream>>>(part2, invbuf, adj, out_img);
}

// Round 6
// 134.331 us; speedup vs baseline: 6.4293x; 1.1935x over previous
//
#include <hip/hip_runtime.h>

#define BD 16
#define EMBD 128
#define H0D 256
#define UPD 512
#define RAD 60
#define PATCHD 120
#define COEFF 1.5f
#define NB 256          // partial-reduction blocks per batch
#define CHUNK 1024      // pixels per partial block (2 rows of 512)
#define SKIPR 32.0f     // 24 (disk) + 8 margin (bilinear/floor reach <= ~3.5)

// ---------------- small helpers ----------------

__device__ __forceinline__ float bsample(const float* __restrict__ img, int H, int W,
                                         float gx, float gy) {
    float xs = ((gx + 1.f) * (float)W - 1.f) * 0.5f;
    float ys = ((gy + 1.f) * (float)H - 1.f) * 0.5f;
    float x0f = floorf(xs), y0f = floorf(ys);
    float wx = xs - x0f, wy = ys - y0f;
    int x0 = (int)x0f, y0 = (int)y0f;
    bool vx0 = (x0 >= 0) && (x0 <= W - 1);
    bool vx1 = (x0 + 1 >= 0) && (x0 + 1 <= W - 1);
    bool vy0 = (y0 >= 0) && (y0 <= H - 1);
    bool vy1 = (y0 + 1 >= 0) && (y0 + 1 <= H - 1);
    int xi0 = min(max(x0, 0), W - 1);
    int xi1 = min(max(x0 + 1, 0), W - 1);
    int yi0 = min(max(y0, 0), H - 1);
    int yi1 = min(max(y0 + 1, 0), H - 1);
    float v00 = (vy0 && vx0) ? img[yi0 * W + xi0] : 0.f;
    float v01 = (vy0 && vx1) ? img[yi0 * W + xi1] : 0.f;
    float v10 = (vy1 && vx0) ? img[yi1 * W + xi0] : 0.f;
    float v11 = (vy1 && vx1) ? img[yi1 * W + xi1] : 0.f;
    return v00 * (1.f - wy) * (1.f - wx) + v01 * (1.f - wy) * wx +
           v10 * wy * (1.f - wx) + v11 * wy * wx;
}

// ---------------- kernels ----------------

__global__ void k_inv(const float* __restrict__ ss, const float* __restrict__ rot,
                      float* __restrict__ invbuf) {
    int b = threadIdx.x;
    if (b < BD) {
        {
            const float* A = ss + b * 6;
            float a = A[0], bb = A[1], c = A[3], d = A[4];
            float det = a * d - bb * c;
            float* o = invbuf + b * 6;
            o[0] = d / det; o[1] = -bb / det; o[2] = 0.f;
            o[3] = -c / det; o[4] = a / det; o[5] = 0.f;
        }
        {
            const float* A = rot + b * 6;
            float a = A[0], bb = A[1], c = A[3], d = A[4];
            float det = a * d - bb * c;
            float* o = invbuf + 96 + b * 6;
            o[0] = d / det; o[1] = -bb / det; o[2] = 0.f;
            o[3] = -c / det; o[4] = a / det; o[5] = 0.f;
        }
    }
}

__global__ __launch_bounds__(256) void k_gemm(const float* __restrict__ kout,
                                              const float* __restrict__ Wd,
                                              float* __restrict__ base) {
    __shared__ float sk[BD * EMBD];
    int t = threadIdx.x;
    for (int i = t; i < BD * EMBD; i += 256) sk[i] = kout[i];
    __syncthreads();
    int n = blockIdx.x * 256 + t;
    float acc[BD];
#pragma unroll
    for (int b = 0; b < BD; b++) acc[b] = 0.f;
    for (int e = 0; e < EMBD; e++) {
        float w = Wd[(size_t)e * (H0D * H0D) + n];
#pragma unroll
        for (int b = 0; b < BD; b++) acc[b] += sk[b * EMBD + e] * w;
    }
#pragma unroll
    for (int b = 0; b < BD; b++)
        base[(size_t)b * (H0D * H0D) + n] = fmaxf(acc[b], 0.f);
}

// bilinear resize 256->512, batch-interleaved block mapping (XCD L2 locality)
__global__ __launch_bounds__(256) void k_resize(const float* __restrict__ base,
                                                float* __restrict__ out) {
    int g = blockIdx.x;
    int b = g & (BD - 1);
    int blk = g >> 4;
    int t = threadIdx.x;
    const float* img = base + (size_t)b * (H0D * H0D);
    float* ob = out + (size_t)b * (UPD * UPD);
    for (int k = 0; k < CHUNK / 256; k++) {
        int p = blk * CHUNK + k * 256 + t;
        int yo = p >> 9, xo = p & 511;
        float ysf = fminf(fmaxf(((float)yo + 0.5f) * 0.5f - 0.5f, 0.f), 255.f);
        float xsf = fminf(fmaxf(((float)xo + 0.5f) * 0.5f - 0.5f, 0.f), 255.f);
        int y0 = (int)floorf(ysf), x0 = (int)floorf(xsf);
        int y1 = min(y0 + 1, H0D - 1), x1 = min(x0 + 1, H0D - 1);
        float wy = ysf - (float)y0, wx = xsf - (float)x0;
        float Ia = img[y0 * H0D + x0], Ib = img[y0 * H0D + x1];
        float Ic = img[y1 * H0D + x0], Id = img[y1 * H0D + x1];
        ob[p] = Ia * (1.f - wy) * (1.f - wx) + Ib * (1.f - wy) * wx +
                Ic * wy * (1.f - wx) + Id * wy * wx;
    }
}

// affine grid-sample, batch-interleaved block mapping
__global__ __launch_bounds__(256) void k_sample(const float* __restrict__ in,
                                                const float* __restrict__ theta,
                                                float* __restrict__ out) {
    int g = blockIdx.x;
    int b = g & (BD - 1);
    int blk = g >> 4;
    int t = threadIdx.x;
    const float* th = theta + b * 6;
    float a0 = th[0], a1 = th[1], a2 = th[2];
    float a3 = th[3], a4 = th[4], a5 = th[5];
    const float* img = in + (size_t)b * (UPD * UPD);
    float* ob = out + (size_t)b * (UPD * UPD);
    for (int k = 0; k < CHUNK / 256; k++) {
        int p = blk * CHUNK + k * 256 + t;
        int yo = p >> 9, xo = p & 511;
        float X = ((float)xo + 0.5f) * (2.f / UPD) - 1.f;
        float Y = ((float)yo + 0.5f) * (2.f / UPD) - 1.f;
        float gx = a0 * X + a1 * Y + a2;
        float gy = a3 * X + a4 * Y + a5;
        ob[p] = bsample(img, UPD, UPD, gx, gy);
    }
}

// pack 4 mask planes into interleaved float4
__global__ void k_pack(const float* __restrict__ masks, float4* __restrict__ packed) {
    int p = blockIdx.x * blockDim.x + threadIdx.x;
    if (p >= UPD * UPD) return;
    float4 v;
    v.x = masks[p];
    v.y = masks[(size_t)(UPD * UPD) + p];
    v.z = masks[(size_t)2 * (UPD * UPD) + p];
    v.w = masks[(size_t)3 * (UPD * UPD) + p];
    packed[p] = v;
}

// All 4 masks: rm_j = (sample(sample(mask_j, inv2), inv1) >= 0.5) with
// analytic strip-skip (composite affine segment vs disk centers).
__global__ __launch_bounds__(256) void k_maskA(
        const float4* __restrict__ packed, const float* __restrict__ invbuf,
        const float* __restrict__ pred_in, uchar4* __restrict__ rm,
        float* __restrict__ part1, unsigned int* __restrict__ flags) {
    int g = blockIdx.x;
    int b = g & (BD - 1);
    int blk = g >> 4;
    int t = threadIdx.x;
    const float* th1 = invbuf + b * 6;        // outer (inv1)
    const float* th2 = invbuf + 96 + b * 6;   // inner (inv2)
    float a10 = th1[0], a11 = th1[1], a12 = th1[2];
    float a13 = th1[3], a14 = th1[4], a15 = th1[5];
    float a20 = th2[0], a21 = th2[1], a22 = th2[2];
    float a23 = th2[3], a24 = th2[4], a25 = th2[5];

    __shared__ unsigned int sflag;
    if (t == 0) {
        const float crow[4] = {160.f, 160.f, 352.f, 352.f};
        const float ccol[4] = {160.f, 352.f, 160.f, 352.f};
        unsigned int f = 0;
        int r0 = blk * 2;
        for (int rr = 0; rr < 2; rr++) {
            float Y = ((float)(r0 + rr) + 0.5f) * (2.f / UPD) - 1.f;
            float X0 = 0.5f * (2.f / UPD) - 1.f;
            float X1 = 511.5f * (2.f / UPD) - 1.f;
            float gx0 = a10 * X0 + a11 * Y + a12, gy0 = a13 * X0 + a14 * Y + a15;
            float gx1 = a10 * X1 + a11 * Y + a12, gy1 = a13 * X1 + a14 * Y + a15;
            float c0 = 256.f * (a20 * gx0 + a21 * gy0 + a22) + 255.5f;
            float w0 = 256.f * (a23 * gx0 + a24 * gy0 + a25) + 255.5f;
            float c1 = 256.f * (a20 * gx1 + a21 * gy1 + a22) + 255.5f;
            float w1 = 256.f * (a23 * gx1 + a24 * gy1 + a25) + 255.5f;
            float vx = c1 - c0, vy = w1 - w0;
            float vv = fmaxf(vx * vx + vy * vy, 1e-12f);
            for (int j = 0; j < 4; j++) {
                float ux = c0 - ccol[j], uy = w0 - crow[j];
                float tt = fminf(fmaxf(-(ux * vx + uy * vy) / vv, 0.f), 1.f);
                float dx = ux + tt * vx, dy = uy + tt * vy;
                if (dx * dx + dy * dy <= SKIPR * SKIPR) f |= (1u << j);
            }
        }
        sflag = f;
        flags[b * NB + blk] = f;
    }
    __syncthreads();
    if (sflag == 0) {
        if (t == 0) {
#pragma unroll
            for (int j = 0; j < 4; j++) {
                part1[((size_t)(j * BD + b) * NB + blk) * 2 + 0] = 0.f;
                part1[((size_t)(j * BD + b) * NB + blk) * 2 + 1] = 0.f;
            }
        }
        return;
    }

    const float* pi = pred_in + (size_t)b * (UPD * UPD);
    uchar4* rmb = rm + (size_t)b * (UPD * UPD);
    float s_new[4] = {0.f, 0.f, 0.f, 0.f};
    float s_m[4] = {0.f, 0.f, 0.f, 0.f};
    int base = blk * CHUNK;
    for (int k = 0; k < CHUNK / 256; k++) {
        int p = base + k * 256 + t;
        int yo = p >> 9, xo = p & 511;
        float X = ((float)xo + 0.5f) * (2.f / UPD) - 1.f;
        float Y = ((float)yo + 0.5f) * (2.f / UPD) - 1.f;
        float gx = a10 * X + a11 * Y + a12;
        float gy = a13 * X + a14 * Y + a15;
        float xs = ((gx + 1.f) * (float)UPD - 1.f) * 0.5f;
        float ys = ((gy + 1.f) * (float)UPD - 1.f) * 0.5f;
        float x0f = floorf(xs), y0f = floorf(ys);
        float wx = xs - x0f, wy = ys - y0f;
        int x0 = (int)x0f, y0 = (int)y0f;
        float r[4][4];  // [neighbor q][mask j]
#pragma unroll
        for (int q = 0; q < 4; q++) {
            int qy = y0 + (q >> 1), qx = x0 + (q & 1);
            bool qv = (qx >= 0) && (qx < UPD) && (qy >= 0) && (qy < UPD);
            if (qv) {
                float Xq = ((float)qx + 0.5f) * (2.f / UPD) - 1.f;
                float Yq = ((float)qy + 0.5f) * (2.f / UPD) - 1.f;
                float g2x = a20 * Xq + a21 * Yq + a22;
                float g2y = a23 * Xq + a24 * Yq + a25;
                float xs2 = ((g2x + 1.f) * (float)UPD - 1.f) * 0.5f;
                float ys2 = ((g2y + 1.f) * (float)UPD - 1.f) * 0.5f;
                float x0f2 = floorf(xs2), y0f2 = floorf(ys2);
                float wx2 = xs2 - x0f2, wy2 = ys2 - y0f2;
                int x02 = (int)x0f2, y02 = (int)y0f2;
                bool vx0 = (x02 >= 0) && (x02 <= UPD - 1);
                bool vx1 = (x02 + 1 >= 0) && (x02 + 1 <= UPD - 1);
                bool vy0 = (y02 >= 0) && (y02 <= UPD - 1);
                bool vy1 = (y02 + 1 >= 0) && (y02 + 1 <= UPD - 1);
                int xi0 = min(max(x02, 0), UPD - 1);
                int xi1 = min(max(x02 + 1, 0), UPD - 1);
                int yi0 = min(max(y02, 0), UPD - 1);
                int yi1 = min(max(y02 + 1, 0), UPD - 1);
                float4 m00 = packed[yi0 * UPD + xi0];
                float4 m01 = packed[yi0 * UPD + xi1];
                float4 m10 = packed[yi1 * UPD + xi0];
                float4 m11 = packed[yi1 * UPD + xi1];
                const float* f00 = (const float*)&m00;
                const float* f01 = (const float*)&m01;
                const float* f10 = (const float*)&m10;
                const float* f11 = (const float*)&m11;
#pragma unroll
                for (int j = 0; j < 4; j++) {
                    float v00 = (vy0 && vx0) ? f00[j] : 0.f;
                    float v01 = (vy0 && vx1) ? f01[j] : 0.f;
                    float v10 = (vy1 && vx0) ? f10[j] : 0.f;
                    float v11 = (vy1 && vx1) ? f11[j] : 0.f;
                    r[q][j] = v00 * (1.f - wy2) * (1.f - wx2) + v01 * (1.f - wy2) * wx2 +
                              v10 * wy2 * (1.f - wx2) + v11 * wy2 * wx2;
                }
            } else {
#pragma unroll
                for (int j = 0; j < 4; j++) r[q][j] = 0.f;
            }
        }
        float piv = pi[p];
        uchar4 rmv;
        unsigned char* rmc = (unsigned char*)&rmv;
#pragma unroll
        for (int j = 0; j < 4; j++) {
            float v = r[0][j] * (1.f - wy) * (1.f - wx) + r[1][j] * (1.f - wy) * wx +
                      r[2][j] * wy * (1.f - wx) + r[3][j] * wy * wx;
            float mm = (v >= 0.5f) ? 1.f : 0.f;
            rmc[j] = (unsigned char)mm;
            s_new[j] += piv * mm;
            s_m[j] += mm;
        }
        rmb[p] = rmv;
    }
    __shared__ float r1[256], r2[256];
    for (int j = 0; j < 4; j++) {
        r1[t] = s_new[j];
        r2[t] = s_m[j];
        __syncthreads();
        for (int s = 128; s > 0; s >>= 1) {
            if (t < s) { r1[t] += r1[t + s]; r2[t] += r2[t + s]; }
            __syncthreads();
        }
        if (t == 0) {
            part1[((size_t)(j * BD + b) * NB + blk) * 2 + 0] = r1[0];
            part1[((size_t)(j * BD + b) * NB + blk) * 2 + 1] = r2[0];
        }
        __syncthreads();
    }
}

// All 4 j: thr (redundant reduce of part1) + centroid partials; strip-skip via flags
__global__ __launch_bounds__(256) void k_maskB(
        const float* __restrict__ pred_in, const uchar4* __restrict__ rm,
        const float* __restrict__ part1, float* __restrict__ part2,
        const unsigned int* __restrict__ flags) {
    int g = blockIdx.x;
    int b = g & (BD - 1);
    int blk = g >> 4;
    int t = threadIdx.x;
    unsigned int flag = flags[b * NB + blk];
    if (flag == 0) {
        if (t == 0) {
#pragma unroll
            for (int j = 0; j < 4; j++) {
                float* o = part2 + ((size_t)(j * BD + b) * NB + blk) * 4;
                o[0] = 0.f; o[1] = 0.f; o[2] = 0.f;
            }
        }
        return;
    }
    __shared__ float r1[256], r2[256], r3[256];
    float thr[4];
    for (int j = 0; j < 4; j++) {
        r1[t] = part1[((size_t)(j * BD + b) * NB + t) * 2 + 0];
        r2[t] = part1[((size_t)(j * BD + b) * NB + t) * 2 + 1];
        __syncthreads();
        for (int s = 128; s > 0; s >>= 1) {
            if (t < s) { r1[t] += r1[t + s]; r2[t] += r2[t + s]; }
            __syncthreads();
        }
        thr[j] = COEFF * (r1[0] / fmaxf(r2[0], 1.f));
        __syncthreads();
    }
    float tot[4] = {0.f, 0.f, 0.f, 0.f};
    float sx[4] = {0.f, 0.f, 0.f, 0.f};
    float sy[4] = {0.f, 0.f, 0.f, 0.f};
    int base = blk * CHUNK;
    const float* pi = pred_in + (size_t)b * (UPD * UPD);
    const uchar4* rmb = rm + (size_t)b * (UPD * UPD);
    for (int k = 0; k < CHUNK / 256; k++) {
        int p = base + k * 256 + t;
        uchar4 mm4 = rmb[p];
        unsigned int mmbits;
        __builtin_memcpy(&mmbits, &mm4, 4);
        if (mmbits == 0) continue;
        float piv = pi[p];
        float fi = (float)(p >> 9), fj = (float)(p & 511);
        const unsigned char* mmc = (const unsigned char*)&mm4;
#pragma unroll
        for (int j = 0; j < 4; j++) {
            float mm = (float)mmc[j];
            float ni = piv * mm;
            bool sel = (mm > 0.f) && (ni > thr[j]);
            float w = sel ? ni : 0.f;
            tot[j] += w;
            sx[j] += w * fi;
            sy[j] += w * fj;
        }
    }
    for (int j = 0; j < 4; j++) {
        r1[t] = tot[j]; r2[t] = sx[j]; r3[t] = sy[j];
        __syncthreads();
        for (int s = 128; s > 0; s >>= 1) {
            if (t < s) { r1[t] += r1[t + s]; r2[t] += r2[t + s]; r3[t] += r3[t + s]; }
            __syncthreads();
        }
        if (t == 0) {
            float* o = part2 + ((size_t)(j * BD + b) * NB + blk) * 4;
            o[0] = r1[0]; o[1] = r2[0]; o[2] = r3[0];
        }
        __syncthreads();
    }
}

// 64 blocks = (b, j). Each block reduces all 4 centroids; if patches are
// pairwise disjoint (the near-rigid-warp common case), each block revises its
// own j concurrently (disjoint pixels). Otherwise block j==0 does the exact
// sequential 4-step path.
__global__ __launch_bounds__(1024) void k_revise(
        const float* __restrict__ part2, const float* __restrict__ invbuf,
        const float* __restrict__ adj, float* __restrict__ img) {
    int b = blockIdx.x >> 2;
    int jown = blockIdx.x & 3;
    int t = threadIdx.x;
    __shared__ float patch[PATCHD * PATCHD];
    __shared__ float red[3][256];
    __shared__ int cshare[8];
    for (int j = 0; j < 4; j++) {
        if (t < 256) {
            const float* pp2 = part2 + ((size_t)(j * BD + b) * NB + t) * 4;
            red[0][t] = pp2[0]; red[1][t] = pp2[1]; red[2][t] = pp2[2];
        }
        __syncthreads();
        for (int s = 128; s > 0; s >>= 1) {
            if (t < s) {
                red[0][t] += red[0][t + s];
                red[1][t] += red[1][t + s];
                red[2][t] += red[2][t + s];
            }
            __syncthreads();
        }
        if (t == 0) {
            float tot = red[0][0] + 1e-8f;
            float cx = red[1][0] / tot;
            float cy = red[2][0] / tot;
            cshare[j * 2 + 0] =
                (int)fminf(fmaxf(rintf(cx), (float)RAD), (float)(UPD - RAD));
            cshare[j * 2 + 1] =
                (int)fminf(fmaxf(rintf(cy), (float)RAD), (float)(UPD - RAD));
        }
        __syncthreads();
    }
    bool overlap = false;
#pragma unroll
    for (int a = 0; a < 4; a++)
#pragma unroll
        for (int c = a + 1; c < 4; c++) {
            int dr = cshare[a * 2] - cshare[c * 2];
            int dc = cshare[a * 2 + 1] - cshare[c * 2 + 1];
            if (dr < 0) dr = -dr;
            if (dc < 0) dc = -dc;
            if (dr < 2 * RAD && dc < 2 * RAD) overlap = true;
        }

    const float* th = invbuf + b * 6;  // inv1
    float th0 = th[0], th1v = th[1], th2v = th[2];
    float th3v = th[3], th4v = th[4], th5v = th[5];
    float a = adj[b];
    float* im = img + (size_t)b * (UPD * UPD);

    int jlo = jown, jhi = jown + 1;
    if (overlap) {
        if (jown != 0) return;
        jlo = 0; jhi = 4;
    }
    for (int j = jlo; j < jhi; j++) {
        int cxi = cshare[j * 2 + 0], cyi = cshare[j * 2 + 1];
        for (int p = t; p < PATCHD * PATCHD; p += 1024) {
            int i = p / PATCHD, jj = p - i * PATCHD;
            float v = im[(cxi - RAD + i) * UPD + (cyi - RAD + jj)];
            int di = i - RAD, dj = jj - RAD;
            if (di * di + dj * dj <= 100) v /= a;  // _DOT = 10
            patch[p] = v;
        }
        __syncthreads();
        for (int p = t; p < PATCHD * PATCHD; p += 1024) {
            int i = p / PATCHD, jj = p - i * PATCHD;
            float X = ((float)jj + 0.5f) * (2.f / PATCHD) - 1.f;
            float Y = ((float)i + 0.5f) * (2.f / PATCHD) - 1.f;
            float gx = th0 * X + th1v * Y + th2v;
            float gy = th3v * X + th4v * Y + th5v;
            float v = bsample(patch, PATCHD, PATCHD, gx, gy);
            im[(cxi - RAD + i) * UPD + (cyi - RAD + jj)] = v;
        }
        __syncthreads();
    }
}

// ---------------- launch ----------------

extern "C" void kernel_launch(void* const* d_in, const int* in_sizes, int n_in,
                              void* d_out, int out_size, void* d_ws, size_t ws_size,
                              hipStream_t stream) {
    const float* x = (const float*)d_in[0];
    const float* k_out = (const float*)d_in[1];
    const float* W_dec = (const float*)d_in[2];
    const float* ss = (const float*)d_in[3];
    const float* rot = (const float*)d_in[4];
    const float* masks = (const float*)d_in[5];
    const float* adj = (const float*)d_in[6];

    float* out = (float*)d_out;
    const size_t NX = (size_t)BD * H0D * H0D;      // 1,048,576
    const size_t P = (size_t)BD * UPD * UPD;       // 4,194,304
    float* out_x = out;
    float* out_base = out + NX;
    float* out_img = out + NX + P;                 // pred_in lives here (pristine
                                                   // until k_revise patches it)

    float* ws = (float*)d_ws;
    float* slotR = ws;                   // pred_rot              (P floats)
    uchar4* rm = (uchar4*)(ws + P);      // BD*512*512 uchar4     (P bytes)
    float* slotC = ws + 2 * P;           // base (P/4 floats)
    float* invbuf = ws + 2 * P + P / 4;  // 192 floats
    float* part1 = invbuf + 192;                  // 4*16*256*2 floats
    float* part2 = part1 + 4 * BD * NB * 2;       // 4*16*256*4 floats
    unsigned int* flags = (unsigned int*)(part2 + 4 * BD * NB * 4);  // 16*256 uints
    float4* packed = (float4*)(flags + BD * NB);  // 512*512 float4 = 4MB

    hipMemcpyAsync(out_x, x, NX * sizeof(float), hipMemcpyDeviceToDevice, stream);

    k_inv<<<1, 64, 0, stream>>>(ss, rot, invbuf);
    float* inv1 = invbuf;
    float* inv2 = invbuf + 96;

    k_pack<<<(UPD * UPD) / 256, 256, 0, stream>>>(masks, packed);
    k_gemm<<<(H0D * H0D) / 256, 256, 0, stream>>>(k_out, W_dec, slotC);
    k_resize<<<BD * NB, 256, 0, stream>>>(slotC, out_base);

    // pred_rot = sample(base_inp, inv2); pred_in = sample(pred_rot, inv1)
    k_sample<<<BD * NB, 256, 0, stream>>>(out_base, inv2, slotR);
    k_sample<<<BD * NB, 256, 0, stream>>>(slotR, inv1, out_img);

    // all 4 masks: fused double-sample + threshold + stats pass 1 (+ strip skip)
    k_maskA<<<BD * NB, 256, 0, stream>>>(packed, invbuf, out_img, rm, part1, flags);
    // all 4 masks: thr + centroid partials
    k_maskB<<<BD * NB, 256, 0, stream>>>(out_img, rm, part1, part2, flags);
    // centroids + revise, parallel over (b, j) with sequential fallback
    k_revise<<<BD * 4, 1024, 0, stream>>>(part2, invbuf, adj, out_img);
}